// Round 12
// baseline (752.613 us; speedup 1.0000x reference)
//
#include <hip/hip_runtime.h>

#define NN 40000
#define NE 640000
#define DF 128
#define NG 2000
#define NCH 157        // ceil(NN/256) node windows
#define GEMM_BLKS 313  // ceil(NN/128)

typedef unsigned int u32;
typedef __attribute__((ext_vector_type(8))) short short8;
typedef __attribute__((ext_vector_type(4))) float floatx4;

// ---- bf16 helpers (packed u32: low 16 = even col, high = odd col) ----
__device__ inline float2 bf2_to_f2(u32 u) {
    return make_float2(__uint_as_float(u << 16), __uint_as_float(u & 0xffff0000u));
}
__device__ inline u32 f_to_bf(float f) {
    u32 u = __float_as_uint(f);
    return (u + 0x7fffu + ((u >> 16) & 1u)) >> 16;   // RNE
}
__device__ inline u32 pack_bf2(float a, float b) {
    return f_to_bf(a) | (f_to_bf(b) << 16);
}
__device__ inline float bf_to_f(short s) {
    return __uint_as_float(((u32)(unsigned short)s) << 16);
}

// ---------------- MFMA GEMM core: out[NxDF bf16] = act(X) @ W ----------------
// block 256 thr (4 waves); tile 128 rows x 128 cols; wave w rows w*32..+31, all 128 cols.
// LDS: 34816B wlds/clds union. WT_F32: stage W from fp32 row-major global in-block.
template<bool BF16IN, bool FUSE_BN, bool WT_F32>
__device__ __forceinline__ void gemm_core(const void* __restrict__ Xv, const void* __restrict__ wsrc,
                                          u32* __restrict__ outb, const float* __restrict__ slots,
                                          const float* __restrict__ gam, const float* __restrict__ bet, int bid) {
    __shared__ unsigned short uni[128 * 136];   // wlds / clds union
    __shared__ float sc[128], sh[128];
    unsigned short* wlds = uni;
    unsigned short* clds = uni;
    int tid = threadIdx.x;
    int row0 = bid * 128;

    if (FUSE_BN) {
        if (tid < 128) {
            float s = 0.f, q = 0.f;
            for (int k = 0; k < 64; k++) {
                s += slots[k * 256 + tid];
                q += slots[k * 256 + 128 + tid];
            }
            const float inv_n = 1.0f / (float)NN;
            float mu = s * inv_n;
            float va = fmaf(-mu, mu, q * inv_n);
            float a = gam[tid] * rsqrtf(va + 1e-5f);
            sc[tid] = a;
            sh[tid] = fmaf(-mu, a, bet[tid]);
        }
    }
    if (WT_F32) {
        const float* W = (const float*)wsrc;     // W[k][c] row-major fp32
        for (int i = tid; i < 16384; i += 256) {
            int k = i >> 7, c = i & 127;
            wlds[c * 136 + k] = (unsigned short)f_to_bf(W[i]);
        }
    } else {
        const unsigned short* wt = (const unsigned short*)wsrc;   // pre-transposed bf16
        for (int i = tid; i < 2048; i += 256) {
            int c = i >> 4, s = i & 15;
            *(uint4*)&wlds[c * 136 + s * 8] = ((const uint4*)wt)[i];
        }
    }
    __syncthreads();

    int lane = tid & 63;
    int wave = tid >> 6;
    int qr = lane >> 4;        // quad: k-offset qr*8
    int rl = lane & 15;        // A row / B col within 16-tile
    int rA0 = row0 + wave * 32 + rl;
    int rA1 = rA0 + 16;
    int rA0c = rA0 < NN ? rA0 : NN - 1;
    int rA1c = rA1 < NN ? rA1 : NN - 1;

    floatx4 acc[2][8];
#pragma unroll
    for (int a = 0; a < 2; a++)
#pragma unroll
        for (int b = 0; b < 8; b++) acc[a][b] = (floatx4){0.f, 0.f, 0.f, 0.f};

#pragma unroll
    for (int kb = 0; kb < 4; kb++) {
        int k0 = kb * 32 + qr * 8;
        short8 a0, a1;
        if (!BF16IN) {
            const float* p0 = (const float*)Xv + (size_t)rA0c * DF + k0;
            const float* p1 = (const float*)Xv + (size_t)rA1c * DF + k0;
            float4 u0 = *(const float4*)p0, u1 = *(const float4*)(p0 + 4);
            float4 v0 = *(const float4*)p1, v1 = *(const float4*)(p1 + 4);
            float fa[8] = {u0.x, u0.y, u0.z, u0.w, u1.x, u1.y, u1.z, u1.w};
            float fb[8] = {v0.x, v0.y, v0.z, v0.w, v1.x, v1.y, v1.z, v1.w};
#pragma unroll
            for (int j = 0; j < 8; j++) { a0[j] = (short)f_to_bf(fa[j]); a1[j] = (short)f_to_bf(fb[j]); }
        } else {
            a0 = *(const short8*)((const u32*)Xv + (size_t)rA0c * 64 + (k0 >> 1));
            a1 = *(const short8*)((const u32*)Xv + (size_t)rA1c * 64 + (k0 >> 1));
            if (FUSE_BN) {
                float4 s0 = *(const float4*)&sc[k0], s1 = *(const float4*)&sc[k0 + 4];
                float4 h0 = *(const float4*)&sh[k0], h1 = *(const float4*)&sh[k0 + 4];
                float ss[8] = {s0.x, s0.y, s0.z, s0.w, s1.x, s1.y, s1.z, s1.w};
                float hh[8] = {h0.x, h0.y, h0.z, h0.w, h1.x, h1.y, h1.z, h1.w};
#pragma unroll
                for (int j = 0; j < 8; j++) {
                    float f0 = fmaxf(fmaf(bf_to_f(a0[j]), ss[j], hh[j]), 0.f);
                    float f1 = fmaxf(fmaf(bf_to_f(a1[j]), ss[j], hh[j]), 0.f);
                    a0[j] = (short)f_to_bf(f0);
                    a1[j] = (short)f_to_bf(f1);
                }
            }
        }
#pragma unroll
        for (int ct = 0; ct < 8; ct++) {
            short8 bfr = *(const short8*)&wlds[(ct * 16 + rl) * 136 + k0];
            acc[0][ct] = __builtin_amdgcn_mfma_f32_16x16x32_bf16(a0, bfr, acc[0][ct], 0, 0, 0);
            acc[1][ct] = __builtin_amdgcn_mfma_f32_16x16x32_bf16(a1, bfr, acc[1][ct], 0, 0, 0);
        }
    }
    __syncthreads();   // all wlds reads done before clds overwrites the union
    // epilogue: C/D layout col=lane&15, row=quad*4+reg -> stage bf16 in LDS, store coalesced
#pragma unroll
    for (int rt = 0; rt < 2; rt++)
#pragma unroll
        for (int ct = 0; ct < 8; ct++)
#pragma unroll
            for (int r = 0; r < 4; r++) {
                int lr = wave * 32 + rt * 16 + qr * 4 + r;
                int c = ct * 16 + rl;
                clds[lr * 136 + c] = (unsigned short)f_to_bf(acc[rt][ct][r]);
            }
    __syncthreads();
    for (int i = tid; i < 2048; i += 256) {
        int lr = i >> 4, s = i & 15;
        int grow = row0 + lr;
        if (grow < NN) {
            uint4 v = *(const uint4*)&clds[lr * 136 + s * 8];
            ((uint4*)(outb + (size_t)grow * 64))[s] = v;
        }
    }
}

// ---------------- window count+rank (157 blocks, NO global atomics) + slot zero (2)
//                  + wt2 transpose (1) + GEMM1 (313) ----------------
// Window block b owns nodes [256b, 256b+256): streams all dst (L2-hot, 2.5MB),
// LDS-histogram + LDS-atomic rank. deg written non-atomically -> no memset needed.
__global__ __launch_bounds__(256, 4) void k_countgemm(const int* __restrict__ dst, int* __restrict__ deg,
                                                      int* __restrict__ rank, float* __restrict__ slots0,
                                                      const float* __restrict__ W1, const float* __restrict__ W2,
                                                      unsigned short* __restrict__ wt2,
                                                      const float* __restrict__ X, u32* __restrict__ outb) {
    __shared__ int wdeg[256];
    int bid = blockIdx.x;
    int tid = threadIdx.x;
    if (bid < NCH) {
        int lo = bid << 8;
        wdeg[tid] = 0;
        __syncthreads();
        const int4* dst4 = (const int4*)dst;
        for (int it = tid; it < NE / 4; it += 256) {
            int4 d = dst4[it];
            int e = it * 4;
            int t0 = d.x - lo, t1 = d.y - lo, t2 = d.z - lo, t3 = d.w - lo;
            if ((u32)t0 < 256u) rank[e]     = atomicAdd(&wdeg[t0], 1);
            if ((u32)t1 < 256u) rank[e + 1] = atomicAdd(&wdeg[t1], 1);
            if ((u32)t2 < 256u) rank[e + 2] = atomicAdd(&wdeg[t2], 1);
            if ((u32)t3 < 256u) rank[e + 3] = atomicAdd(&wdeg[t3], 1);
        }
        __syncthreads();
        int node = lo + tid;
        if (node < NN) deg[node] = wdeg[tid];
        return;
    }
    if (bid < NCH + 2) {       // zero slotsA+slotsB (consumed 2+ dispatches later)
        float* s = slots0 + (bid - NCH) * 64 * 256;
        for (int i = tid; i < 64 * 256; i += 256) s[i] = 0.f;
        return;
    }
    if (bid == NCH + 2) {      // wt2 transpose (consumed by k_gemm2, later dispatch)
        for (int i = tid; i < 128 * 128; i += 256) {
            int k = i >> 7, c = i & 127;
            wt2[c * 128 + k] = (unsigned short)f_to_bf(W2[i]);
        }
        return;
    }
    gemm_core<false, false, true>(X, W1, outb, nullptr, nullptr, nullptr, bid - NCH - 3);
}

// ---------------- scan + fill merged: 157 window blocks ----------------
// phase1: base = redundant sum deg[0..256b) (coalesced, L2-hot)
// phase2: LDS scan of own window -> row_ptr, dis; keep rowp in LDS
// phase3: re-stream dst; for own-window edges: col[rowp[d]+rank[e]] = src[e] (atomic-free)
__global__ __launch_bounds__(256) void k_scanfill(const int* __restrict__ deg,
                                                  const int* __restrict__ src, const int* __restrict__ dst,
                                                  const int* __restrict__ rank,
                                                  int* __restrict__ row_ptr, float* __restrict__ dis,
                                                  int* __restrict__ col) {
    __shared__ int red[256];
    __shared__ int ls[256];
    __shared__ int rowp[256];
    int tid = threadIdx.x;
    int blk = blockIdx.x;
    int lo = blk << 8;
    int partial = 0;
    for (int i = tid; i < lo; i += 256) partial += deg[i];
    red[tid] = partial;
    int i = lo + tid;
    int d = (i < NN) ? deg[i] : 0;
    ls[tid] = d;
    __syncthreads();
#pragma unroll
    for (int off = 128; off > 0; off >>= 1) {
        if (tid < off) red[tid] += red[tid + off];
        __syncthreads();
    }
    int base = red[0];
#pragma unroll
    for (int off = 1; off < 256; off <<= 1) {
        int t = (tid >= off) ? ls[tid - off] : 0;
        __syncthreads();
        ls[tid] += t;
        __syncthreads();
    }
    int r = base + ls[tid] - d;   // global exclusive prefix
    rowp[tid] = r;
    if (i < NN) {
        row_ptr[i] = r;
        dis[i] = rsqrtf((float)(d + 1));
    }
    if (blk == NCH - 1 && tid == 0) row_ptr[NN] = NE;
    __syncthreads();
    // phase3: fill own window
    const int4* dst4 = (const int4*)dst;
    for (int it = tid; it < NE / 4; it += 256) {
        int4 dd = dst4[it];
        int e = it * 4;
        int t0 = dd.x - lo, t1 = dd.y - lo, t2 = dd.z - lo, t3 = dd.w - lo;
        if ((u32)t0 < 256u) col[rowp[t0] + rank[e]]     = src[e];
        if ((u32)t1 < 256u) col[rowp[t1] + rank[e + 1]] = src[e + 1];
        if ((u32)t2 < 256u) col[rowp[t2] + rank[e + 2]] = src[e + 2];
        if ((u32)t3 < 256u) col[rowp[t3] + rank[e + 3]] = src[e + 3];
    }
}

__global__ __launch_bounds__(256, 4) void k_gemm2(const u32* __restrict__ Hb, const unsigned short* __restrict__ wt2,
                                                  u32* __restrict__ outb, const float* __restrict__ slots,
                                                  const float* __restrict__ gam, const float* __restrict__ bet) {
    gemm_core<true, true, false>(Hb, wt2, outb, slots, gam, bet, blockIdx.x);
}

// ---------------- GCN aggregation: one wave/node, 4 nodes/block; BN-stats fused ----------------
__global__ __launch_bounds__(256) void k_gather(const u32* __restrict__ Hb, const int* __restrict__ row_ptr,
                                                const int* __restrict__ col, const float* __restrict__ dis,
                                                const float* __restrict__ bias, u32* __restrict__ outb,
                                                float* __restrict__ slots) {
    __shared__ float sred[4][128];
    __shared__ float qred[4][128];
    int t = threadIdx.x & 63;                       // lane: cols 2t, 2t+1
    int wv = threadIdx.x >> 6;
    int node = blockIdx.x * 4 + wv;
    float di = dis[node];
    float2 acc;
    {
        float2 a = bf2_to_f2(Hb[(size_t)node * 64 + t]);
        float s = di * di;
        acc = make_float2(a.x * s, a.y * s);
    }
    int lo = row_ptr[node], hi = row_ptr[node + 1];
    for (int base = lo; base < hi; base += 64) {
        int m = hi - base; if (m > 64) m = 64;
        int sidx = 0; float sw = 0.f;
        if (t < m) { sidx = col[base + t]; sw = di * dis[sidx]; }
        int j = 0;
        for (; j + 8 <= m; j += 8) {
            int s0 = __shfl(sidx, j),     s1 = __shfl(sidx, j + 1);
            int s2 = __shfl(sidx, j + 2), s3 = __shfl(sidx, j + 3);
            int s4 = __shfl(sidx, j + 4), s5 = __shfl(sidx, j + 5);
            int s6 = __shfl(sidx, j + 6), s7 = __shfl(sidx, j + 7);
            float w0 = __shfl(sw, j),     w1 = __shfl(sw, j + 1);
            float w2 = __shfl(sw, j + 2), w3 = __shfl(sw, j + 3);
            float w4 = __shfl(sw, j + 4), w5 = __shfl(sw, j + 5);
            float w6 = __shfl(sw, j + 6), w7 = __shfl(sw, j + 7);
            u32 u0 = Hb[(size_t)s0 * 64 + t], u1 = Hb[(size_t)s1 * 64 + t];
            u32 u2 = Hb[(size_t)s2 * 64 + t], u3 = Hb[(size_t)s3 * 64 + t];
            u32 u4 = Hb[(size_t)s4 * 64 + t], u5 = Hb[(size_t)s5 * 64 + t];
            u32 u6 = Hb[(size_t)s6 * 64 + t], u7 = Hb[(size_t)s7 * 64 + t];
            float2 h0 = bf2_to_f2(u0), h1 = bf2_to_f2(u1), h2 = bf2_to_f2(u2), h3 = bf2_to_f2(u3);
            float2 h4 = bf2_to_f2(u4), h5 = bf2_to_f2(u5), h6 = bf2_to_f2(u6), h7 = bf2_to_f2(u7);
            acc.x = fmaf(h3.x, w3, fmaf(h2.x, w2, fmaf(h1.x, w1, fmaf(h0.x, w0, acc.x))));
            acc.y = fmaf(h3.y, w3, fmaf(h2.y, w2, fmaf(h1.y, w1, fmaf(h0.y, w0, acc.y))));
            acc.x = fmaf(h7.x, w7, fmaf(h6.x, w6, fmaf(h5.x, w5, fmaf(h4.x, w4, acc.x))));
            acc.y = fmaf(h7.y, w7, fmaf(h6.y, w6, fmaf(h5.y, w5, fmaf(h4.y, w4, acc.y))));
        }
        for (; j < m; j++) {
            int s0 = __shfl(sidx, j); float w0 = __shfl(sw, j);
            float2 h0 = bf2_to_f2(Hb[(size_t)s0 * 64 + t]);
            acc.x = fmaf(h0.x, w0, acc.x);
            acc.y = fmaf(h0.y, w0, acc.y);
        }
    }
    float2 b = ((const float2*)bias)[t];
    acc.x += b.x; acc.y += b.y;
    outb[(size_t)node * 64 + t] = pack_bf2(acc.x, acc.y);
    // BN stats (pre-BN activations, incl. bias): block reduce -> 64-slot atomics
    sred[wv][2 * t] = acc.x;     sred[wv][2 * t + 1] = acc.y;
    qred[wv][2 * t] = acc.x * acc.x; qred[wv][2 * t + 1] = acc.y * acc.y;
    __syncthreads();
    int tid = threadIdx.x;
    if (tid < 128) {
        float s = sred[0][tid] + sred[1][tid] + sred[2][tid] + sred[3][tid];
        float q = qred[0][tid] + qred[1][tid] + qred[2][tid] + qred[3][tid];
        int slot = blockIdx.x & 63;
        atomicAdd(&slots[slot * 256 + tid], s);
        atomicAdd(&slots[slot * 256 + 128 + tid], q);
    }
}

// ---------------- pool (BN2+ReLU) + fc1 + fc2 + fc3, 4 graphs per block ----------------
__global__ __launch_bounds__(256) void k_poolfc(const u32* __restrict__ Hb, const int* __restrict__ batch,
                                                const float* __restrict__ slots,
                                                const float* __restrict__ gam, const float* __restrict__ bet,
                                                const float* __restrict__ fc1w, const float* __restrict__ fc1b,
                                                const float* __restrict__ fc2w, const float* __restrict__ fc2b,
                                                const float* __restrict__ fc3w, const float* __restrict__ fc3b,
                                                float* __restrict__ out) {
    __shared__ float sc[128], sh[128];
    __shared__ float pooled[4][128];
    __shared__ float g1[4][256];
    __shared__ float g2[4][256];
    __shared__ int bnds[5];
    int tid = threadIdx.x;
    int gbase = blockIdx.x * 4;
    if (tid < 128) {
        float s = 0.f, q = 0.f;
        for (int k = 0; k < 64; k++) {
            s += slots[k * 256 + tid];
            q += slots[k * 256 + 128 + tid];
        }
        const float inv_n = 1.0f / (float)NN;
        float mu = s * inv_n;
        float va = fmaf(-mu, mu, q * inv_n);
        float a = gam[tid] * rsqrtf(va + 1e-5f);
        sc[tid] = a;
        sh[tid] = fmaf(-mu, a, bet[tid]);
    } else if (tid < 133) {
        int target = gbase + (tid - 128);
        int a = 0, b = NN;
        while (a < b) { int m = (a + b) >> 1; if (batch[m] < target) a = m + 1; else b = m; }
        bnds[tid - 128] = a;
    }
    __syncthreads();
    // pooling: wave per graph, lane p -> cols 2p,2p+1
    {
        int g = tid >> 6, p = tid & 63;
        int lo = bnds[g], hi = bnds[g + 1];
        float a0 = 0.f, a1 = 0.f;
        float sc0 = sc[2 * p], sh0 = sh[2 * p], sc1 = sc[2 * p + 1], sh1 = sh[2 * p + 1];
        for (int i = lo; i < hi; i++) {
            float2 v = bf2_to_f2(Hb[(size_t)i * 64 + p]);
            a0 += fmaxf(fmaf(v.x, sc0, sh0), 0.f);
            a1 += fmaxf(fmaf(v.y, sc1, sh1), 0.f);
        }
        pooled[g][2 * p] = a0;
        pooled[g][2 * p + 1] = a1;
    }
    __syncthreads();
    // fc1: K=128 -> 256
    {
        float x0 = 0.f, x1 = 0.f, x2 = 0.f, x3 = 0.f;
        for (int k = 0; k < 128; k++) {
            float wv = fc1w[k * 256 + tid];
            x0 = fmaf(pooled[0][k], wv, x0);
            x1 = fmaf(pooled[1][k], wv, x1);
            x2 = fmaf(pooled[2][k], wv, x2);
            x3 = fmaf(pooled[3][k], wv, x3);
        }
        float bb = fc1b[tid];
        g1[0][tid] = fmaxf(x0 + bb, 0.f);
        g1[1][tid] = fmaxf(x1 + bb, 0.f);
        g1[2][tid] = fmaxf(x2 + bb, 0.f);
        g1[3][tid] = fmaxf(x3 + bb, 0.f);
    }
    __syncthreads();
    // fc2: K=256 -> 256
    {
        float x0 = 0.f, x1 = 0.f, x2 = 0.f, x3 = 0.f;
        for (int k = 0; k < 256; k++) {
            float wv = fc2w[k * 256 + tid];
            x0 = fmaf(g1[0][k], wv, x0);
            x1 = fmaf(g1[1][k], wv, x1);
            x2 = fmaf(g1[2][k], wv, x2);
            x3 = fmaf(g1[3][k], wv, x3);
        }
        float bb = fc2b[tid];
        g2[0][tid] = fmaxf(x0 + bb, 0.f);
        g2[1][tid] = fmaxf(x1 + bb, 0.f);
        g2[2][tid] = fmaxf(x2 + bb, 0.f);
        g2[3][tid] = fmaxf(x3 + bb, 0.f);
    }
    __syncthreads();
    // fc3: wave per graph -> scalar
    {
        int lane = tid & 63, wv = tid >> 6;
        float s = fmaf(g2[wv][lane], fc3w[lane],
                  fmaf(g2[wv][64 + lane], fc3w[64 + lane],
                  fmaf(g2[wv][128 + lane], fc3w[128 + lane],
                       g2[wv][192 + lane] * fc3w[192 + lane])));
        for (int off = 32; off > 0; off >>= 1) s += __shfl_down(s, off);
        if (lane == 0) out[gbase + wv] = s + fc3b[0];
    }
}

extern "C" void kernel_launch(void* const* d_in, const int* in_sizes, int n_in,
                              void* d_out, int out_size, void* d_ws, size_t ws_size,
                              hipStream_t stream) {
    const float* x    = (const float*)d_in[0];
    const int*   ei   = (const int*)d_in[1];
    const int*   batch= (const int*)d_in[2];
    const float* W1   = (const float*)d_in[4];
    const float* b1   = (const float*)d_in[5];
    const float* W2   = (const float*)d_in[6];
    const float* b2   = (const float*)d_in[7];
    const float* bn1g = (const float*)d_in[8];
    const float* bn1b = (const float*)d_in[9];
    const float* bn2g = (const float*)d_in[10];
    const float* bn2b = (const float*)d_in[11];
    const float* fc1w = (const float*)d_in[12];
    const float* fc1b = (const float*)d_in[13];
    const float* fc2w = (const float*)d_in[14];
    const float* fc2b = (const float*)d_in[15];
    const float* fc3w = (const float*)d_in[16];
    const float* fc3b = (const float*)d_in[17];
    const int* src = ei;
    const int* dst = ei + NE;
    float* outp = (float*)d_out;

    char* w = (char*)d_ws;
    size_t o = 0;
    auto alloc = [&](size_t bytes) -> char* {
        char* p = w + o;
        o = (o + bytes + 255) & ~(size_t)255;
        return p;
    };
    int*   deg     = (int*)alloc((size_t)NN * 4);
    float* slots0  = (float*)alloc((size_t)2 * 64 * 256 * 4);   // slotsA | slotsB (zeroed in-kernel)
    int*   row_ptr = (int*)alloc((size_t)(NN + 1) * 4);
    int*   rank    = (int*)alloc((size_t)NE * 4);
    int*   col     = (int*)alloc((size_t)NE * 4);
    float* dis     = (float*)alloc((size_t)NN * 4);
    unsigned short* wt2 = (unsigned short*)alloc(128 * 128 * 2);
    u32*   bufA    = (u32*)alloc((size_t)NN * 64 * 4);
    u32*   bufB    = (u32*)alloc((size_t)NN * 64 * 4);
    float* slotsA  = slots0;
    float* slotsB  = slots0 + 64 * 256;

    k_countgemm<<<NCH + 3 + GEMM_BLKS, 256, 0, stream>>>(dst, deg, rank, slots0, W1, W2, wt2, x, bufA);
    k_scanfill<<<NCH, 256, 0, stream>>>(deg, src, dst, rank, row_ptr, dis, col);
    k_gather<<<NN / 4, 256, 0, stream>>>(bufA, row_ptr, col, dis, b1, bufB, slotsA);
    k_gemm2<<<GEMM_BLKS, 256, 0, stream>>>(bufB, wt2, bufA, slotsA, bn1g, bn1b);
    k_gather<<<NN / 4, 256, 0, stream>>>(bufA, row_ptr, col, dis, b2, bufB, slotsB);
    k_poolfc<<<NG / 4, 256, 0, stream>>>(bufB, batch, slotsB, bn2g, bn2b,
                                         fc1w, fc1b, fc2w, fc2b, fc3w, fc3b, outp);
}

// Round 13
// 273.270 us; speedup vs baseline: 2.7541x; 2.7541x over previous
//
#include <hip/hip_runtime.h>
#include <hip/hip_fp16.h>

#define NN 40000
#define NE 640000
#define DF 128
#define NG 2000
#define NCH 157        // ceil(NN/256) chunks
#define FILLB 625      // NE / (256*4) edge blocks, 4 edges/thread
#define GEMM_BLKS 625  // NN / 64 (exact)

typedef unsigned int u32;
typedef __attribute__((ext_vector_type(8))) short short8;
typedef __attribute__((ext_vector_type(4))) float floatx4;

// ---- bf16 helpers (packed u32: low 16 = even col, high = odd col) ----
__device__ inline float2 bf2_to_f2(u32 u) {
    return make_float2(__uint_as_float(u << 16), __uint_as_float(u & 0xffff0000u));
}
__device__ inline u32 f_to_bf(float f) {
    u32 u = __float_as_uint(f);
    return (u + 0x7fffu + ((u >> 16) & 1u)) >> 16;   // RNE
}
__device__ inline u32 pack_bf2(float a, float b) {
    return f_to_bf(a) | (f_to_bf(b) << 16);
}
__device__ inline float bf_to_f(short s) {
    return __uint_as_float(((u32)(unsigned short)s) << 16);
}
// packed col entry: low 16 = src index (<65536), high 16 = fp16(dis[src])
__device__ inline float colw_to_f(int cw) {
    return __half2float(__ushort_as_half((unsigned short)((u32)cw >> 16)));
}

// ---------------- MFMA GEMM core: out[NxDF bf16] = act(X) @ W ----------------
// 64-row x 128-col tile, 4 waves (wave w: rows w*16..+15). 625 blocks -> ~2.4/CU
// (the 128-row/313-block version left half the CUs with one block).
// LDS: wlds(128x136 Wt) UNION clds(64x136 C-stage) = 34816B.
// WT_F32: stage W from fp32 row-major global in-block (GEMM1, no wt buffer race).
template<bool BF16IN, bool FUSE_BN, bool WT_F32>
__device__ __forceinline__ void gemm_core(const void* __restrict__ Xv, const void* __restrict__ wsrc,
                                          u32* __restrict__ outb, const float* __restrict__ slots,
                                          const float* __restrict__ gam, const float* __restrict__ bet, int bid) {
    __shared__ unsigned short uni[128 * 136];
    __shared__ float sc[128], sh[128];
    unsigned short* wlds = uni;
    unsigned short* clds = uni;
    int tid = threadIdx.x;
    int row0 = bid * 64;

    if (FUSE_BN) {
        if (tid < 128) {
            float s = 0.f, q = 0.f;
            for (int k = 0; k < 64; k++) {
                s += slots[k * 256 + tid];
                q += slots[k * 256 + 128 + tid];
            }
            const float inv_n = 1.0f / (float)NN;
            float mu = s * inv_n;
            float va = fmaf(-mu, mu, q * inv_n);
            float a = gam[tid] * rsqrtf(va + 1e-5f);
            sc[tid] = a;
            sh[tid] = fmaf(-mu, a, bet[tid]);
        }
    }
    // stage W into wlds[c][k], row stride 136 u16
    if (WT_F32) {
        const float* W = (const float*)wsrc;     // W[k][c] row-major fp32
        for (int i = tid; i < 16384; i += 256) {
            int k = i >> 7, c = i & 127;
            wlds[c * 136 + k] = (unsigned short)f_to_bf(W[i]);
        }
    } else {
        const unsigned short* wt = (const unsigned short*)wsrc;   // pre-transposed bf16
        for (int i = tid; i < 2048; i += 256) {
            int c = i >> 4, s = i & 15;
            *(uint4*)&wlds[c * 136 + s * 8] = ((const uint4*)wt)[i];
        }
    }
    __syncthreads();

    int lane = tid & 63;
    int wave = tid >> 6;
    int qr = lane >> 4;        // quad: k-offset qr*8
    int rl = lane & 15;        // A row / B col within 16-tile
    int rA = row0 + wave * 16 + rl;   // < NN always (625*64 == NN)

    floatx4 acc[8];
#pragma unroll
    for (int b = 0; b < 8; b++) acc[b] = (floatx4){0.f, 0.f, 0.f, 0.f};

#pragma unroll
    for (int kb = 0; kb < 4; kb++) {
        int k0 = kb * 32 + qr * 8;
        short8 a0;
        if (!BF16IN) {
            const float* p0 = (const float*)Xv + (size_t)rA * DF + k0;
            float4 u0 = *(const float4*)p0, u1 = *(const float4*)(p0 + 4);
            float fa[8] = {u0.x, u0.y, u0.z, u0.w, u1.x, u1.y, u1.z, u1.w};
#pragma unroll
            for (int j = 0; j < 8; j++) a0[j] = (short)f_to_bf(fa[j]);
        } else {
            a0 = *(const short8*)((const u32*)Xv + (size_t)rA * 64 + (k0 >> 1));
            if (FUSE_BN) {
                float4 s0 = *(const float4*)&sc[k0], s1 = *(const float4*)&sc[k0 + 4];
                float4 h0 = *(const float4*)&sh[k0], h1 = *(const float4*)&sh[k0 + 4];
                float ss[8] = {s0.x, s0.y, s0.z, s0.w, s1.x, s1.y, s1.z, s1.w};
                float hh[8] = {h0.x, h0.y, h0.z, h0.w, h1.x, h1.y, h1.z, h1.w};
#pragma unroll
                for (int j = 0; j < 8; j++) {
                    float f0 = fmaxf(fmaf(bf_to_f(a0[j]), ss[j], hh[j]), 0.f);
                    a0[j] = (short)f_to_bf(f0);
                }
            }
        }
#pragma unroll
        for (int ct = 0; ct < 8; ct++) {
            short8 bfr = *(const short8*)&wlds[(ct * 16 + rl) * 136 + k0];
            acc[ct] = __builtin_amdgcn_mfma_f32_16x16x32_bf16(a0, bfr, acc[ct], 0, 0, 0);
        }
    }
    __syncthreads();   // all wlds reads done before clds overwrites the union
    // C/D layout col=lane&15, row=quad*4+reg -> stage bf16 in LDS, store coalesced
#pragma unroll
    for (int ct = 0; ct < 8; ct++)
#pragma unroll
        for (int r = 0; r < 4; r++) {
            int lr = wave * 16 + qr * 4 + r;
            int c = ct * 16 + rl;
            clds[lr * 136 + c] = (unsigned short)f_to_bf(acc[ct][r]);
        }
    __syncthreads();
    for (int i = tid; i < 1024; i += 256) {
        int lr = i >> 4, s = i & 15;
        uint4 v = *(const uint4*)&clds[lr * 136 + s * 8];
        ((uint4*)(outb + (size_t)(row0 + lr) * 64))[s] = v;
    }
}

// ---------------- count+rank (625 blocks, 4 edges/thread) + wt2 transpose (1) + GEMM1 (625) ----------------
// rank[e] = old value of deg[dst[e]] -> fill pass is atomic-free.
// 640k global atomics = ~45us floor (measured r7/r9/r10: invariant to ILP & target spread).
__global__ __launch_bounds__(256, 4) void k_countgemm(const int* __restrict__ dst, int* __restrict__ deg,
                                                      int* __restrict__ rank,
                                                      const float* __restrict__ W1, const float* __restrict__ W2,
                                                      unsigned short* __restrict__ wt2,
                                                      const float* __restrict__ X, u32* __restrict__ outb) {
    int bid = blockIdx.x;
    if (bid < FILLB) {
        int e0 = bid * 1024 + threadIdx.x;
        int d0 = dst[e0], d1 = dst[e0 + 256], d2 = dst[e0 + 512], d3 = dst[e0 + 768];
        int r0 = atomicAdd(&deg[d0], 1);
        int r1 = atomicAdd(&deg[d1], 1);
        int r2 = atomicAdd(&deg[d2], 1);
        int r3 = atomicAdd(&deg[d3], 1);
        rank[e0] = r0;
        rank[e0 + 256] = r1;
        rank[e0 + 512] = r2;
        rank[e0 + 768] = r3;
        return;
    }
    if (bid == FILLB) {
        for (int i = threadIdx.x; i < 128 * 128; i += 256) {
            int k = i >> 7, c = i & 127;
            wt2[c * 128 + k] = (unsigned short)f_to_bf(W2[i]);   // consumed by k_gemm2 (later dispatch)
        }
        return;
    }
    gemm_core<false, false, true>(X, W1, outb, nullptr, nullptr, nullptr, bid - FILLB - 1);
}

// ---------------- scan: 157 blocks; block b redundantly sums deg[0..256b) (L2-hot 160KB) ----------------
__global__ __launch_bounds__(256) void k_scan(const int* __restrict__ deg,
                                              int* __restrict__ row_ptr, float* __restrict__ dis) {
    __shared__ int red[256];
    __shared__ int ls[256];
    int tid = threadIdx.x;
    int blk = blockIdx.x;
    int limit = blk * 256;
    int partial = 0;
    for (int i = tid; i < limit; i += 256) partial += deg[i];
    red[tid] = partial;
    int i = limit + tid;
    int d = (i < NN) ? deg[i] : 0;
    ls[tid] = d;
    __syncthreads();
#pragma unroll
    for (int off = 128; off > 0; off >>= 1) {
        if (tid < off) red[tid] += red[tid + off];
        __syncthreads();
    }
    int base = red[0];
#pragma unroll
    for (int off = 1; off < 256; off <<= 1) {
        int t = (tid >= off) ? ls[tid - off] : 0;
        __syncthreads();
        ls[tid] += t;
        __syncthreads();
    }
    if (i < NN) {
        int r = base + ls[tid] - d;   // global exclusive prefix
        row_ptr[i] = r;
        dis[i] = rsqrtf((float)(d + 1));
    }
    if (blk == NCH - 1 && tid == 0) row_ptr[NN] = NE;
}

// ---------------- CSR fill: atomic-free; packs fp16(dis[src]) into col high bits ----------------
// Pays the random dis[src] gather ONCE here (high occupancy) instead of twice in the gathers.
__global__ __launch_bounds__(256) void k_fill(const int* __restrict__ src, const int* __restrict__ dst,
                                              const int* __restrict__ rank, const int* __restrict__ row_ptr,
                                              const float* __restrict__ dis, u32* __restrict__ col) {
    int e0 = blockIdx.x * 1024 + threadIdx.x;
    int d0 = dst[e0], d1 = dst[e0 + 256], d2 = dst[e0 + 512], d3 = dst[e0 + 768];
    int s0 = src[e0], s1 = src[e0 + 256], s2 = src[e0 + 512], s3 = src[e0 + 768];
    int r0 = rank[e0], r1 = rank[e0 + 256], r2 = rank[e0 + 512], r3 = rank[e0 + 768];
    u32 h0 = (u32)__half_as_ushort(__float2half(dis[s0]));
    u32 h1 = (u32)__half_as_ushort(__float2half(dis[s1]));
    u32 h2 = (u32)__half_as_ushort(__float2half(dis[s2]));
    u32 h3 = (u32)__half_as_ushort(__float2half(dis[s3]));
    col[row_ptr[d0] + r0] = (u32)s0 | (h0 << 16);
    col[row_ptr[d1] + r1] = (u32)s1 | (h1 << 16);
    col[row_ptr[d2] + r2] = (u32)s2 | (h2 << 16);
    col[row_ptr[d3] + r3] = (u32)s3 | (h3 << 16);
}

__global__ __launch_bounds__(256, 4) void k_gemm2(const u32* __restrict__ Hb, const unsigned short* __restrict__ wt2,
                                                  u32* __restrict__ outb, const float* __restrict__ slots,
                                                  const float* __restrict__ gam, const float* __restrict__ bet) {
    gemm_core<true, true, false>(Hb, wt2, outb, slots, gam, bet, blockIdx.x);
}

// ---------------- GCN aggregation: one wave/node, 4 nodes/block; BN-stats fused ----------------
// col entries carry the fp16 source norm -> no random dis gather, 1 shfl per edge.
__global__ __launch_bounds__(256) void k_gather(const u32* __restrict__ Hb, const int* __restrict__ row_ptr,
                                                const u32* __restrict__ col, const float* __restrict__ dis,
                                                const float* __restrict__ bias, u32* __restrict__ outb,
                                                float* __restrict__ slots) {
    __shared__ float sred[4][128];
    __shared__ float qred[4][128];
    int t = threadIdx.x & 63;                       // lane: cols 2t, 2t+1
    int wv = threadIdx.x >> 6;
    int node = blockIdx.x * 4 + wv;
    float di = dis[node];
    float2 acc;
    {
        float2 a = bf2_to_f2(Hb[(size_t)node * 64 + t]);
        float s = di * di;
        acc = make_float2(a.x * s, a.y * s);
    }
    int lo = row_ptr[node], hi = row_ptr[node + 1];
    for (int base = lo; base < hi; base += 64) {
        int m = hi - base; if (m > 64) m = 64;
        int cw = 0;
        if (t < m) cw = (int)col[base + t];
        int j = 0;
        for (; j + 8 <= m; j += 8) {
            int c0 = __shfl(cw, j),     c1 = __shfl(cw, j + 1);
            int c2 = __shfl(cw, j + 2), c3 = __shfl(cw, j + 3);
            int c4 = __shfl(cw, j + 4), c5 = __shfl(cw, j + 5);
            int c6 = __shfl(cw, j + 6), c7 = __shfl(cw, j + 7);
            u32 u0 = Hb[(size_t)(c0 & 0xffff) * 64 + t], u1 = Hb[(size_t)(c1 & 0xffff) * 64 + t];
            u32 u2 = Hb[(size_t)(c2 & 0xffff) * 64 + t], u3 = Hb[(size_t)(c3 & 0xffff) * 64 + t];
            u32 u4 = Hb[(size_t)(c4 & 0xffff) * 64 + t], u5 = Hb[(size_t)(c5 & 0xffff) * 64 + t];
            u32 u6 = Hb[(size_t)(c6 & 0xffff) * 64 + t], u7 = Hb[(size_t)(c7 & 0xffff) * 64 + t];
            float w0 = di * colw_to_f(c0), w1 = di * colw_to_f(c1);
            float w2 = di * colw_to_f(c2), w3 = di * colw_to_f(c3);
            float w4 = di * colw_to_f(c4), w5 = di * colw_to_f(c5);
            float w6 = di * colw_to_f(c6), w7 = di * colw_to_f(c7);
            float2 h0 = bf2_to_f2(u0), h1 = bf2_to_f2(u1), h2 = bf2_to_f2(u2), h3 = bf2_to_f2(u3);
            float2 h4 = bf2_to_f2(u4), h5 = bf2_to_f2(u5), h6 = bf2_to_f2(u6), h7 = bf2_to_f2(u7);
            acc.x = fmaf(h3.x, w3, fmaf(h2.x, w2, fmaf(h1.x, w1, fmaf(h0.x, w0, acc.x))));
            acc.y = fmaf(h3.y, w3, fmaf(h2.y, w2, fmaf(h1.y, w1, fmaf(h0.y, w0, acc.y))));
            acc.x = fmaf(h7.x, w7, fmaf(h6.x, w6, fmaf(h5.x, w5, fmaf(h4.x, w4, acc.x))));
            acc.y = fmaf(h7.y, w7, fmaf(h6.y, w6, fmaf(h5.y, w5, fmaf(h4.y, w4, acc.y))));
        }
        for (; j < m; j++) {
            int c0 = __shfl(cw, j);
            float w0 = di * colw_to_f(c0);
            float2 h0 = bf2_to_f2(Hb[(size_t)(c0 & 0xffff) * 64 + t]);
            acc.x = fmaf(h0.x, w0, acc.x);
            acc.y = fmaf(h0.y, w0, acc.y);
        }
    }
    float2 b = ((const float2*)bias)[t];
    acc.x += b.x; acc.y += b.y;
    outb[(size_t)node * 64 + t] = pack_bf2(acc.x, acc.y);
    // BN stats (pre-BN activations, incl. bias): block reduce -> 64-slot atomics
    sred[wv][2 * t] = acc.x;     sred[wv][2 * t + 1] = acc.y;
    qred[wv][2 * t] = acc.x * acc.x; qred[wv][2 * t + 1] = acc.y * acc.y;
    __syncthreads();
    int tid = threadIdx.x;
    if (tid < 128) {
        float s = sred[0][tid] + sred[1][tid] + sred[2][tid] + sred[3][tid];
        float q = qred[0][tid] + qred[1][tid] + qred[2][tid] + qred[3][tid];
        int slot = blockIdx.x & 63;
        atomicAdd(&slots[slot * 256 + tid], s);
        atomicAdd(&slots[slot * 256 + 128 + tid], q);
    }
}

// ---------------- pool (BN2+ReLU) + fc1 + fc2 + fc3, 4 graphs per block ----------------
__global__ __launch_bounds__(256) void k_poolfc(const u32* __restrict__ Hb, const int* __restrict__ batch,
                                                const float* __restrict__ slots,
                                                const float* __restrict__ gam, const float* __restrict__ bet,
                                                const float* __restrict__ fc1w, const float* __restrict__ fc1b,
                                                const float* __restrict__ fc2w, const float* __restrict__ fc2b,
                                                const float* __restrict__ fc3w, const float* __restrict__ fc3b,
                                                float* __restrict__ out) {
    __shared__ float sc[128], sh[128];
    __shared__ float pooled[4][128];
    __shared__ float g1[4][256];
    __shared__ float g2[4][256];
    __shared__ int bnds[5];
    int tid = threadIdx.x;
    int gbase = blockIdx.x * 4;
    if (tid < 128) {
        float s = 0.f, q = 0.f;
        for (int k = 0; k < 64; k++) {
            s += slots[k * 256 + tid];
            q += slots[k * 256 + 128 + tid];
        }
        const float inv_n = 1.0f / (float)NN;
        float mu = s * inv_n;
        float va = fmaf(-mu, mu, q * inv_n);
        float a = gam[tid] * rsqrtf(va + 1e-5f);
        sc[tid] = a;
        sh[tid] = fmaf(-mu, a, bet[tid]);
    } else if (tid < 133) {
        int target = gbase + (tid - 128);
        int a = 0, b = NN;
        while (a < b) { int m = (a + b) >> 1; if (batch[m] < target) a = m + 1; else b = m; }
        bnds[tid - 128] = a;
    }
    __syncthreads();
    // pooling: wave per graph, lane p -> cols 2p,2p+1
    {
        int g = tid >> 6, p = tid & 63;
        int lo = bnds[g], hi = bnds[g + 1];
        float a0 = 0.f, a1 = 0.f;
        float sc0 = sc[2 * p], sh0 = sh[2 * p], sc1 = sc[2 * p + 1], sh1 = sh[2 * p + 1];
        for (int i = lo; i < hi; i++) {
            float2 v = bf2_to_f2(Hb[(size_t)i * 64 + p]);
            a0 += fmaxf(fmaf(v.x, sc0, sh0), 0.f);
            a1 += fmaxf(fmaf(v.y, sc1, sh1), 0.f);
        }
        pooled[g][2 * p] = a0;
        pooled[g][2 * p + 1] = a1;
    }
    __syncthreads();
    // fc1: K=128 -> 256
    {
        float x0 = 0.f, x1 = 0.f, x2 = 0.f, x3 = 0.f;
        for (int k = 0; k < 128; k++) {
            float wv = fc1w[k * 256 + tid];
            x0 = fmaf(pooled[0][k], wv, x0);
            x1 = fmaf(pooled[1][k], wv, x1);
            x2 = fmaf(pooled[2][k], wv, x2);
            x3 = fmaf(pooled[3][k], wv, x3);
        }
        float bb = fc1b[tid];
        g1[0][tid] = fmaxf(x0 + bb, 0.f);
        g1[1][tid] = fmaxf(x1 + bb, 0.f);
        g1[2][tid] = fmaxf(x2 + bb, 0.f);
        g1[3][tid] = fmaxf(x3 + bb, 0.f);
    }
    __syncthreads();
    // fc2: K=256 -> 256
    {
        float x0 = 0.f, x1 = 0.f, x2 = 0.f, x3 = 0.f;
        for (int k = 0; k < 256; k++) {
            float wv = fc2w[k * 256 + tid];
            x0 = fmaf(g1[0][k], wv, x0);
            x1 = fmaf(g1[1][k], wv, x1);
            x2 = fmaf(g1[2][k], wv, x2);
            x3 = fmaf(g1[3][k], wv, x3);
        }
        float bb = fc2b[tid];
        g2[0][tid] = fmaxf(x0 + bb, 0.f);
        g2[1][tid] = fmaxf(x1 + bb, 0.f);
        g2[2][tid] = fmaxf(x2 + bb, 0.f);
        g2[3][tid] = fmaxf(x3 + bb, 0.f);
    }
    __syncthreads();
    // fc3: wave per graph -> scalar
    {
        int lane = tid & 63, wv = tid >> 6;
        float s = fmaf(g2[wv][lane], fc3w[lane],
                  fmaf(g2[wv][64 + lane], fc3w[64 + lane],
                  fmaf(g2[wv][128 + lane], fc3w[128 + lane],
                       g2[wv][192 + lane] * fc3w[192 + lane])));
        for (int off = 32; off > 0; off >>= 1) s += __shfl_down(s, off);
        if (lane == 0) out[gbase + wv] = s + fc3b[0];
    }
}

extern "C" void kernel_launch(void* const* d_in, const int* in_sizes, int n_in,
                              void* d_out, int out_size, void* d_ws, size_t ws_size,
                              hipStream_t stream) {
    const float* x    = (const float*)d_in[0];
    const int*   ei   = (const int*)d_in[1];
    const int*   batch= (const int*)d_in[2];
    const float* W1   = (const float*)d_in[4];
    const float* b1   = (const float*)d_in[5];
    const float* W2   = (const float*)d_in[6];
    const float* b2   = (const float*)d_in[7];
    const float* bn1g = (const float*)d_in[8];
    const float* bn1b = (const float*)d_in[9];
    const float* bn2g = (const float*)d_in[10];
    const float* bn2b = (const float*)d_in[11];
    const float* fc1w = (const float*)d_in[12];
    const float* fc1b = (const float*)d_in[13];
    const float* fc2w = (const float*)d_in[14];
    const float* fc2b = (const float*)d_in[15];
    const float* fc3w = (const float*)d_in[16];
    const float* fc3b = (const float*)d_in[17];
    const int* src = ei;
    const int* dst = ei + NE;
    float* outp = (float*)d_out;

    char* w = (char*)d_ws;
    size_t o = 0;
    auto alloc = [&](size_t bytes) -> char* {
        char* p = w + o;
        o = (o + bytes + 255) & ~(size_t)255;
        return p;
    };
    // zero region: deg + slotsA + slotsB (contiguous)
    int*   deg     = (int*)alloc((size_t)NN * 4);
    float* slotsA  = (float*)alloc(64 * 256 * 4);
    float* slotsB  = (float*)alloc(64 * 256 * 4);
    char*  zend    = w + o;
    int*   row_ptr = (int*)alloc((size_t)(NN + 1) * 4);
    int*   rank    = (int*)alloc((size_t)NE * 4);
    u32*   col     = (u32*)alloc((size_t)NE * 4);
    float* dis     = (float*)alloc((size_t)NN * 4);
    unsigned short* wt2 = (unsigned short*)alloc(128 * 128 * 2);
    u32*   bufA    = (u32*)alloc((size_t)NN * 64 * 4);
    u32*   bufB    = (u32*)alloc((size_t)NN * 64 * 4);

    hipMemsetAsync(deg, 0, (size_t)(zend - (char*)deg), stream);

    k_countgemm<<<FILLB + 1 + GEMM_BLKS, 256, 0, stream>>>(dst, deg, rank, W1, W2, wt2, x, bufA);
    k_scan<<<NCH, 256, 0, stream>>>(deg, row_ptr, dis);
    k_fill<<<FILLB, 256, 0, stream>>>(src, dst, rank, row_ptr, dis, col);
    k_gather<<<NN / 4, 256, 0, stream>>>(bufA, row_ptr, col, dis, b1, bufB, slotsA);
    k_gemm2<<<GEMM_BLKS, 256, 0, stream>>>(bufB, wt2, bufA, slotsA, bn1g, bn1b);
    k_gather<<<NN / 4, 256, 0, stream>>>(bufA, row_ptr, col, dis, b2, bufB, slotsB);
    k_poolfc<<<NG / 4, 256, 0, stream>>>(bufB, batch, slotsB, bn2g, bn2b,
                                         fc1w, fc1b, fc2w, fc2b, fc3w, fc3b, outp);
}

// Round 14
// 272.783 us; speedup vs baseline: 2.7590x; 1.0018x over previous
//
#include <hip/hip_runtime.h>
#include <hip/hip_fp16.h>

#define NN 40000
#define NE 640000
#define DF 128
#define NG 2000
#define NCH 157        // ceil(NN/256) chunks
#define FILLB 625      // NE / (256*4) edge blocks, 4 edges/thread
#define G1_BLKS 313    // ceil(NN/128) -- GEMM1 128-row tiles (halves W-staging count)
#define G2_BLKS 625    // NN/64 -- GEMM2 64-row tiles (occupancy balance)

typedef unsigned int u32;
typedef __attribute__((ext_vector_type(8))) short short8;
typedef __attribute__((ext_vector_type(4))) float floatx4;

// ---- bf16 helpers (packed u32: low 16 = even col, high = odd col) ----
__device__ inline float2 bf2_to_f2(u32 u) {
    return make_float2(__uint_as_float(u << 16), __uint_as_float(u & 0xffff0000u));
}
__device__ inline u32 f_to_bf(float f) {
    u32 u = __float_as_uint(f);
    return (u + 0x7fffu + ((u >> 16) & 1u)) >> 16;   // RNE
}
__device__ inline u32 pack_bf2(float a, float b) {
    return f_to_bf(a) | (f_to_bf(b) << 16);
}
__device__ inline float bf_to_f(short s) {
    return __uint_as_float(((u32)(unsigned short)s) << 16);
}
// packed col entry: low 16 = src index (<65536), high 16 = fp16(dis[src])
__device__ inline float colw_to_f(int cw) {
    return __half2float(__ushort_as_half((unsigned short)((u32)cw >> 16)));
}

// ---------------- MFMA GEMM core: out[NxDF bf16] = act(X) @ W ----------------
// TILE128: 128-row tile (acc[2][8], rows may need clamp).  else 64-row tile (exact).
// LDS: wlds(128x136 Wt) UNION clds = 34816B.
// WT_F32: stage W from fp32 row-major global in-block (GEMM1 -- no wt-buffer race;
//         8-way-conflict writes cost ~1us/313 blocks, acceptable).
template<bool BF16IN, bool FUSE_BN, bool WT_F32, bool TILE128>
__device__ __forceinline__ void gemm_core(const void* __restrict__ Xv, const void* __restrict__ wsrc,
                                          u32* __restrict__ outb, const float* __restrict__ slots,
                                          const float* __restrict__ gam, const float* __restrict__ bet, int bid) {
    __shared__ unsigned short uni[128 * 136];
    __shared__ float sc[128], sh[128];
    unsigned short* wlds = uni;
    unsigned short* clds = uni;
    int tid = threadIdx.x;
    int row0 = bid * (TILE128 ? 128 : 64);

    if (FUSE_BN) {
        if (tid < 128) {
            float s = 0.f, q = 0.f;
            for (int k = 0; k < 64; k++) {
                s += slots[k * 256 + tid];
                q += slots[k * 256 + 128 + tid];
            }
            const float inv_n = 1.0f / (float)NN;
            float mu = s * inv_n;
            float va = fmaf(-mu, mu, q * inv_n);
            float a = gam[tid] * rsqrtf(va + 1e-5f);
            sc[tid] = a;
            sh[tid] = fmaf(-mu, a, bet[tid]);
        }
    }
    // stage W into wlds[c][k], row stride 136 u16
    if (WT_F32) {
        const float* W = (const float*)wsrc;     // W[k][c] row-major fp32
        for (int i = tid; i < 16384; i += 256) {
            int k = i >> 7, c = i & 127;
            wlds[c * 136 + k] = (unsigned short)f_to_bf(W[i]);
        }
    } else {
        const unsigned short* wt = (const unsigned short*)wsrc;   // pre-transposed bf16
        for (int i = tid; i < 2048; i += 256) {
            int c = i >> 4, s = i & 15;
            *(uint4*)&wlds[c * 136 + s * 8] = ((const uint4*)wt)[i];
        }
    }
    __syncthreads();

    int lane = tid & 63;
    int wave = tid >> 6;
    int qr = lane >> 4;        // quad: k-offset qr*8
    int rl = lane & 15;        // A row / B col within 16-tile

    if (TILE128) {
        int rA0 = row0 + wave * 32 + rl;
        int rA1 = rA0 + 16;
        int rA0c = rA0 < NN ? rA0 : NN - 1;
        int rA1c = rA1 < NN ? rA1 : NN - 1;
        floatx4 acc[2][8];
#pragma unroll
        for (int a = 0; a < 2; a++)
#pragma unroll
            for (int b = 0; b < 8; b++) acc[a][b] = (floatx4){0.f, 0.f, 0.f, 0.f};
#pragma unroll
        for (int kb = 0; kb < 4; kb++) {
            int k0 = kb * 32 + qr * 8;
            short8 a0, a1;
            if (!BF16IN) {
                const float* p0 = (const float*)Xv + (size_t)rA0c * DF + k0;
                const float* p1 = (const float*)Xv + (size_t)rA1c * DF + k0;
                float4 u0 = *(const float4*)p0, u1 = *(const float4*)(p0 + 4);
                float4 v0 = *(const float4*)p1, v1 = *(const float4*)(p1 + 4);
                float fa[8] = {u0.x, u0.y, u0.z, u0.w, u1.x, u1.y, u1.z, u1.w};
                float fb[8] = {v0.x, v0.y, v0.z, v0.w, v1.x, v1.y, v1.z, v1.w};
#pragma unroll
                for (int j = 0; j < 8; j++) { a0[j] = (short)f_to_bf(fa[j]); a1[j] = (short)f_to_bf(fb[j]); }
            } else {
                a0 = *(const short8*)((const u32*)Xv + (size_t)rA0c * 64 + (k0 >> 1));
                a1 = *(const short8*)((const u32*)Xv + (size_t)rA1c * 64 + (k0 >> 1));
                if (FUSE_BN) {
#pragma unroll
                    for (int j = 0; j < 8; j++) {
                        float f0 = fmaxf(fmaf(bf_to_f(a0[j]), sc[k0 + j], sh[k0 + j]), 0.f);
                        float f1 = fmaxf(fmaf(bf_to_f(a1[j]), sc[k0 + j], sh[k0 + j]), 0.f);
                        a0[j] = (short)f_to_bf(f0);
                        a1[j] = (short)f_to_bf(f1);
                    }
                }
            }
#pragma unroll
            for (int ct = 0; ct < 8; ct++) {
                short8 bfr = *(const short8*)&wlds[(ct * 16 + rl) * 136 + k0];
                acc[0][ct] = __builtin_amdgcn_mfma_f32_16x16x32_bf16(a0, bfr, acc[0][ct], 0, 0, 0);
                acc[1][ct] = __builtin_amdgcn_mfma_f32_16x16x32_bf16(a1, bfr, acc[1][ct], 0, 0, 0);
            }
        }
        __syncthreads();
#pragma unroll
        for (int rt = 0; rt < 2; rt++)
#pragma unroll
            for (int ct = 0; ct < 8; ct++)
#pragma unroll
                for (int r = 0; r < 4; r++) {
                    int lr = wave * 32 + rt * 16 + qr * 4 + r;
                    int c = ct * 16 + rl;
                    clds[lr * 136 + c] = (unsigned short)f_to_bf(acc[rt][ct][r]);
                }
        __syncthreads();
        for (int i = tid; i < 2048; i += 256) {
            int lr = i >> 4, s = i & 15;
            int grow = row0 + lr;
            if (grow < NN) {
                uint4 v = *(const uint4*)&clds[lr * 136 + s * 8];
                ((uint4*)(outb + (size_t)grow * 64))[s] = v;
            }
        }
    } else {
        int rA = row0 + wave * 16 + rl;   // < NN always (625*64 == NN)
        floatx4 acc[8];
#pragma unroll
        for (int b = 0; b < 8; b++) acc[b] = (floatx4){0.f, 0.f, 0.f, 0.f};
#pragma unroll
        for (int kb = 0; kb < 4; kb++) {
            int k0 = kb * 32 + qr * 8;
            short8 a0;
            if (!BF16IN) {
                const float* p0 = (const float*)Xv + (size_t)rA * DF + k0;
                float4 u0 = *(const float4*)p0, u1 = *(const float4*)(p0 + 4);
                float fa[8] = {u0.x, u0.y, u0.z, u0.w, u1.x, u1.y, u1.z, u1.w};
#pragma unroll
                for (int j = 0; j < 8; j++) a0[j] = (short)f_to_bf(fa[j]);
            } else {
                a0 = *(const short8*)((const u32*)Xv + (size_t)rA * 64 + (k0 >> 1));
                if (FUSE_BN) {
#pragma unroll
                    for (int j = 0; j < 8; j++) {
                        float f0 = fmaxf(fmaf(bf_to_f(a0[j]), sc[k0 + j], sh[k0 + j]), 0.f);
                        a0[j] = (short)f_to_bf(f0);
                    }
                }
            }
#pragma unroll
            for (int ct = 0; ct < 8; ct++) {
                short8 bfr = *(const short8*)&wlds[(ct * 16 + rl) * 136 + k0];
                acc[ct] = __builtin_amdgcn_mfma_f32_16x16x32_bf16(a0, bfr, acc[ct], 0, 0, 0);
            }
        }
        __syncthreads();
#pragma unroll
        for (int ct = 0; ct < 8; ct++)
#pragma unroll
            for (int r = 0; r < 4; r++) {
                int lr = wave * 16 + qr * 4 + r;
                int c = ct * 16 + rl;
                clds[lr * 136 + c] = (unsigned short)f_to_bf(acc[ct][r]);
            }
        __syncthreads();
        for (int i = tid; i < 1024; i += 256) {
            int lr = i >> 4, s = i & 15;
            uint4 v = *(const uint4*)&clds[lr * 136 + s * 8];
            ((uint4*)(outb + (size_t)(row0 + lr) * 64))[s] = v;
        }
    }
}

// ---------------- count+rank (625 blocks) + wt2 transpose (1) + GEMM1 (313, 128-row) ----------------
// rank[e] = old deg value -> atomic-free fill. 640k global atomics = ~46us floor
// (measured r7/r9/r10/r13: invariant to ILP, target spread, occupancy).
__global__ __launch_bounds__(256, 4) void k_countgemm(const int* __restrict__ dst, int* __restrict__ deg,
                                                      int* __restrict__ rank,
                                                      const float* __restrict__ W1, const float* __restrict__ W2,
                                                      unsigned short* __restrict__ wt2,
                                                      const float* __restrict__ X, u32* __restrict__ outb) {
    int bid = blockIdx.x;
    if (bid < FILLB) {
        int e0 = bid * 1024 + threadIdx.x;
        int d0 = dst[e0], d1 = dst[e0 + 256], d2 = dst[e0 + 512], d3 = dst[e0 + 768];
        int r0 = atomicAdd(&deg[d0], 1);
        int r1 = atomicAdd(&deg[d1], 1);
        int r2 = atomicAdd(&deg[d2], 1);
        int r3 = atomicAdd(&deg[d3], 1);
        rank[e0] = r0;
        rank[e0 + 256] = r1;
        rank[e0 + 512] = r2;
        rank[e0 + 768] = r3;
        return;
    }
    if (bid == FILLB) {
        for (int i = threadIdx.x; i < 128 * 128; i += 256) {
            int k = i >> 7, c = i & 127;
            wt2[c * 128 + k] = (unsigned short)f_to_bf(W2[i]);   // consumed by k_gemm2 (later dispatch)
        }
        return;
    }
    gemm_core<false, false, true, true>(X, W1, outb, nullptr, nullptr, nullptr, bid - FILLB - 1);
}

// ---------------- scan: 157 blocks; block b redundantly sums deg[0..256b) (L2-hot 160KB) ----------------
__global__ __launch_bounds__(256) void k_scan(const int* __restrict__ deg,
                                              int* __restrict__ row_ptr, float* __restrict__ dis) {
    __shared__ int red[256];
    __shared__ int ls[256];
    int tid = threadIdx.x;
    int blk = blockIdx.x;
    int limit = blk * 256;
    int partial = 0;
    for (int i = tid; i < limit; i += 256) partial += deg[i];
    red[tid] = partial;
    int i = limit + tid;
    int d = (i < NN) ? deg[i] : 0;
    ls[tid] = d;
    __syncthreads();
#pragma unroll
    for (int off = 128; off > 0; off >>= 1) {
        if (tid < off) red[tid] += red[tid + off];
        __syncthreads();
    }
    int base = red[0];
#pragma unroll
    for (int off = 1; off < 256; off <<= 1) {
        int t = (tid >= off) ? ls[tid - off] : 0;
        __syncthreads();
        ls[tid] += t;
        __syncthreads();
    }
    if (i < NN) {
        int r = base + ls[tid] - d;   // global exclusive prefix
        row_ptr[i] = r;
        dis[i] = rsqrtf((float)(d + 1));
    }
    if (blk == NCH - 1 && tid == 0) row_ptr[NN] = NE;
}

// ---------------- CSR fill: atomic-free; packs fp16(dis[src]) into col high bits ----------------
__global__ __launch_bounds__(256) void k_fill(const int* __restrict__ src, const int* __restrict__ dst,
                                              const int* __restrict__ rank, const int* __restrict__ row_ptr,
                                              const float* __restrict__ dis, u32* __restrict__ col) {
    int e0 = blockIdx.x * 1024 + threadIdx.x;
    int d0 = dst[e0], d1 = dst[e0 + 256], d2 = dst[e0 + 512], d3 = dst[e0 + 768];
    int s0 = src[e0], s1 = src[e0 + 256], s2 = src[e0 + 512], s3 = src[e0 + 768];
    int r0 = rank[e0], r1 = rank[e0 + 256], r2 = rank[e0 + 512], r3 = rank[e0 + 768];
    u32 h0 = (u32)__half_as_ushort(__float2half(dis[s0]));
    u32 h1 = (u32)__half_as_ushort(__float2half(dis[s1]));
    u32 h2 = (u32)__half_as_ushort(__float2half(dis[s2]));
    u32 h3 = (u32)__half_as_ushort(__float2half(dis[s3]));
    col[row_ptr[d0] + r0] = (u32)s0 | (h0 << 16);
    col[row_ptr[d1] + r1] = (u32)s1 | (h1 << 16);
    col[row_ptr[d2] + r2] = (u32)s2 | (h2 << 16);
    col[row_ptr[d3] + r3] = (u32)s3 | (h3 << 16);
}

__global__ __launch_bounds__(256, 4) void k_gemm2(const u32* __restrict__ Hb, const unsigned short* __restrict__ wt2,
                                                  u32* __restrict__ outb, const float* __restrict__ slots,
                                                  const float* __restrict__ gam, const float* __restrict__ bet) {
    gemm_core<true, true, false, false>(Hb, wt2, outb, slots, gam, bet, blockIdx.x);
}

// ---------------- GCN aggregation: one wave/node, 4 nodes/block; BN-stats fused ----------------
__global__ __launch_bounds__(256) void k_gather(const u32* __restrict__ Hb, const int* __restrict__ row_ptr,
                                                const u32* __restrict__ col, const float* __restrict__ dis,
                                                const float* __restrict__ bias, u32* __restrict__ outb,
                                                float* __restrict__ slots) {
    __shared__ float sred[4][128];
    __shared__ float qred[4][128];
    int t = threadIdx.x & 63;                       // lane: cols 2t, 2t+1
    int wv = threadIdx.x >> 6;
    int node = blockIdx.x * 4 + wv;
    float di = dis[node];
    float2 acc;
    {
        float2 a = bf2_to_f2(Hb[(size_t)node * 64 + t]);
        float s = di * di;
        acc = make_float2(a.x * s, a.y * s);
    }
    int lo = row_ptr[node], hi = row_ptr[node + 1];
    for (int base = lo; base < hi; base += 64) {
        int m = hi - base; if (m > 64) m = 64;
        int cw = 0;
        if (t < m) cw = (int)col[base + t];
        int j = 0;
        for (; j + 8 <= m; j += 8) {
            int c0 = __shfl(cw, j),     c1 = __shfl(cw, j + 1);
            int c2 = __shfl(cw, j + 2), c3 = __shfl(cw, j + 3);
            int c4 = __shfl(cw, j + 4), c5 = __shfl(cw, j + 5);
            int c6 = __shfl(cw, j + 6), c7 = __shfl(cw, j + 7);
            u32 u0 = Hb[(size_t)(c0 & 0xffff) * 64 + t], u1 = Hb[(size_t)(c1 & 0xffff) * 64 + t];
            u32 u2 = Hb[(size_t)(c2 & 0xffff) * 64 + t], u3 = Hb[(size_t)(c3 & 0xffff) * 64 + t];
            u32 u4 = Hb[(size_t)(c4 & 0xffff) * 64 + t], u5 = Hb[(size_t)(c5 & 0xffff) * 64 + t];
            u32 u6 = Hb[(size_t)(c6 & 0xffff) * 64 + t], u7 = Hb[(size_t)(c7 & 0xffff) * 64 + t];
            float w0 = di * colw_to_f(c0), w1 = di * colw_to_f(c1);
            float w2 = di * colw_to_f(c2), w3 = di * colw_to_f(c3);
            float w4 = di * colw_to_f(c4), w5 = di * colw_to_f(c5);
            float w6 = di * colw_to_f(c6), w7 = di * colw_to_f(c7);
            float2 h0 = bf2_to_f2(u0), h1 = bf2_to_f2(u1), h2 = bf2_to_f2(u2), h3 = bf2_to_f2(u3);
            float2 h4 = bf2_to_f2(u4), h5 = bf2_to_f2(u5), h6 = bf2_to_f2(u6), h7 = bf2_to_f2(u7);
            acc.x = fmaf(h3.x, w3, fmaf(h2.x, w2, fmaf(h1.x, w1, fmaf(h0.x, w0, acc.x))));
            acc.y = fmaf(h3.y, w3, fmaf(h2.y, w2, fmaf(h1.y, w1, fmaf(h0.y, w0, acc.y))));
            acc.x = fmaf(h7.x, w7, fmaf(h6.x, w6, fmaf(h5.x, w5, fmaf(h4.x, w4, acc.x))));
            acc.y = fmaf(h7.y, w7, fmaf(h6.y, w6, fmaf(h5.y, w5, fmaf(h4.y, w4, acc.y))));
        }
        for (; j < m; j++) {
            int c0 = __shfl(cw, j);
            float w0 = di * colw_to_f(c0);
            float2 h0 = bf2_to_f2(Hb[(size_t)(c0 & 0xffff) * 64 + t]);
            acc.x = fmaf(h0.x, w0, acc.x);
            acc.y = fmaf(h0.y, w0, acc.y);
        }
    }
    float2 b = ((const float2*)bias)[t];
    acc.x += b.x; acc.y += b.y;
    outb[(size_t)node * 64 + t] = pack_bf2(acc.x, acc.y);
    // BN stats (pre-BN activations, incl. bias): block reduce -> 64-slot atomics
    sred[wv][2 * t] = acc.x;     sred[wv][2 * t + 1] = acc.y;
    qred[wv][2 * t] = acc.x * acc.x; qred[wv][2 * t + 1] = acc.y * acc.y;
    __syncthreads();
    int tid = threadIdx.x;
    if (tid < 128) {
        float s = sred[0][tid] + sred[1][tid] + sred[2][tid] + sred[3][tid];
        float q = qred[0][tid] + qred[1][tid] + qred[2][tid] + qred[3][tid];
        int slot = blockIdx.x & 63;
        atomicAdd(&slots[slot * 256 + tid], s);
        atomicAdd(&slots[slot * 256 + 128 + tid], q);
    }
}

// ---------------- pool (BN2+ReLU) + fc1 + fc2 + fc3, 4 graphs per block ----------------
__global__ __launch_bounds__(256) void k_poolfc(const u32* __restrict__ Hb, const int* __restrict__ batch,
                                                const float* __restrict__ slots,
                                                const float* __restrict__ gam, const float* __restrict__ bet,
                                                const float* __restrict__ fc1w, const float* __restrict__ fc1b,
                                                const float* __restrict__ fc2w, const float* __restrict__ fc2b,
                                                const float* __restrict__ fc3w, const float* __restrict__ fc3b,
                                                float* __restrict__ out) {
    __shared__ float sc[128], sh[128];
    __shared__ float pooled[4][128];
    __shared__ float g1[4][256];
    __shared__ float g2[4][256];
    __shared__ int bnds[5];
    int tid = threadIdx.x;
    int gbase = blockIdx.x * 4;
    if (tid < 128) {
        float s = 0.f, q = 0.f;
        for (int k = 0; k < 64; k++) {
            s += slots[k * 256 + tid];
            q += slots[k * 256 + 128 + tid];
        }
        const float inv_n = 1.0f / (float)NN;
        float mu = s * inv_n;
        float va = fmaf(-mu, mu, q * inv_n);
        float a = gam[tid] * rsqrtf(va + 1e-5f);
        sc[tid] = a;
        sh[tid] = fmaf(-mu, a, bet[tid]);
    } else if (tid < 133) {
        int target = gbase + (tid - 128);
        int a = 0, b = NN;
        while (a < b) { int m = (a + b) >> 1; if (batch[m] < target) a = m + 1; else b = m; }
        bnds[tid - 128] = a;
    }
    __syncthreads();
    // pooling: wave per graph, lane p -> cols 2p,2p+1
    {
        int g = tid >> 6, p = tid & 63;
        int lo = bnds[g], hi = bnds[g + 1];
        float a0 = 0.f, a1 = 0.f;
        float sc0 = sc[2 * p], sh0 = sh[2 * p], sc1 = sc[2 * p + 1], sh1 = sh[2 * p + 1];
        for (int i = lo; i < hi; i++) {
            float2 v = bf2_to_f2(Hb[(size_t)i * 64 + p]);
            a0 += fmaxf(fmaf(v.x, sc0, sh0), 0.f);
            a1 += fmaxf(fmaf(v.y, sc1, sh1), 0.f);
        }
        pooled[g][2 * p] = a0;
        pooled[g][2 * p + 1] = a1;
    }
    __syncthreads();
    // fc1: K=128 -> 256
    {
        float x0 = 0.f, x1 = 0.f, x2 = 0.f, x3 = 0.f;
        for (int k = 0; k < 128; k++) {
            float wv = fc1w[k * 256 + tid];
            x0 = fmaf(pooled[0][k], wv, x0);
            x1 = fmaf(pooled[1][k], wv, x1);
            x2 = fmaf(pooled[2][k], wv, x2);
            x3 = fmaf(pooled[3][k], wv, x3);
        }
        float bb = fc1b[tid];
        g1[0][tid] = fmaxf(x0 + bb, 0.f);
        g1[1][tid] = fmaxf(x1 + bb, 0.f);
        g1[2][tid] = fmaxf(x2 + bb, 0.f);
        g1[3][tid] = fmaxf(x3 + bb, 0.f);
    }
    __syncthreads();
    // fc2: K=256 -> 256
    {
        float x0 = 0.f, x1 = 0.f, x2 = 0.f, x3 = 0.f;
        for (int k = 0; k < 256; k++) {
            float wv = fc2w[k * 256 + tid];
            x0 = fmaf(g1[0][k], wv, x0);
            x1 = fmaf(g1[1][k], wv, x1);
            x2 = fmaf(g1[2][k], wv, x2);
            x3 = fmaf(g1[3][k], wv, x3);
        }
        float bb = fc2b[tid];
        g2[0][tid] = fmaxf(x0 + bb, 0.f);
        g2[1][tid] = fmaxf(x1 + bb, 0.f);
        g2[2][tid] = fmaxf(x2 + bb, 0.f);
        g2[3][tid] = fmaxf(x3 + bb, 0.f);
    }
    __syncthreads();
    // fc3: wave per graph -> scalar
    {
        int lane = tid & 63, wv = tid >> 6;
        float s = fmaf(g2[wv][lane], fc3w[lane],
                  fmaf(g2[wv][64 + lane], fc3w[64 + lane],
                  fmaf(g2[wv][128 + lane], fc3w[128 + lane],
                       g2[wv][192 + lane] * fc3w[192 + lane])));
        for (int off = 32; off > 0; off >>= 1) s += __shfl_down(s, off);
        if (lane == 0) out[gbase + wv] = s + fc3b[0];
    }
}

extern "C" void kernel_launch(void* const* d_in, const int* in_sizes, int n_in,
                              void* d_out, int out_size, void* d_ws, size_t ws_size,
                              hipStream_t stream) {
    const float* x    = (const float*)d_in[0];
    const int*   ei   = (const int*)d_in[1];
    const int*   batch= (const int*)d_in[2];
    const float* W1   = (const float*)d_in[4];
    const float* b1   = (const float*)d_in[5];
    const float* W2   = (const float*)d_in[6];
    const float* b2   = (const float*)d_in[7];
    const float* bn1g = (const float*)d_in[8];
    const float* bn1b = (const float*)d_in[9];
    const float* bn2g = (const float*)d_in[10];
    const float* bn2b = (const float*)d_in[11];
    const float* fc1w = (const float*)d_in[12];
    const float* fc1b = (const float*)d_in[13];
    const float* fc2w = (const float*)d_in[14];
    const float* fc2b = (const float*)d_in[15];
    const float* fc3w = (const float*)d_in[16];
    const float* fc3b = (const float*)d_in[17];
    const int* src = ei;
    const int* dst = ei + NE;
    float* outp = (float*)d_out;

    char* w = (char*)d_ws;
    size_t o = 0;
    auto alloc = [&](size_t bytes) -> char* {
        char* p = w + o;
        o = (o + bytes + 255) & ~(size_t)255;
        return p;
    };
    // zero region: deg + slotsA + slotsB (contiguous)
    int*   deg     = (int*)alloc((size_t)NN * 4);
    float* slotsA  = (float*)alloc(64 * 256 * 4);
    float* slotsB  = (float*)alloc(64 * 256 * 4);
    char*  zend    = w + o;
    int*   row_ptr = (int*)alloc((size_t)(NN + 1) * 4);
    int*   rank    = (int*)alloc((size_t)NE * 4);
    u32*   col     = (u32*)alloc((size_t)NE * 4);
    float* dis     = (float*)alloc((size_t)NN * 4);
    unsigned short* wt2 = (unsigned short*)alloc(128 * 128 * 2);
    u32*   bufA    = (u32*)alloc((size_t)NN * 64 * 4);
    u32*   bufB    = (u32*)alloc((size_t)NN * 64 * 4);

    hipMemsetAsync(deg, 0, (size_t)(zend - (char*)deg), stream);

    k_countgemm<<<FILLB + 1 + G1_BLKS, 256, 0, stream>>>(dst, deg, rank, W1, W2, wt2, x, bufA);
    k_scan<<<NCH, 256, 0, stream>>>(deg, row_ptr, dis);
    k_fill<<<FILLB, 256, 0, stream>>>(src, dst, rank, row_ptr, dis, col);
    k_gather<<<NN / 4, 256, 0, stream>>>(bufA, row_ptr, col, dis, b1, bufB, slotsA);
    k_gemm2<<<G2_BLKS, 256, 0, stream>>>(bufB, wt2, bufA, slotsA, bn1g, bn1b);
    k_gather<<<NN / 4, 256, 0, stream>>>(bufA, row_ptr, col, dis, b2, bufB, slotsB);
    k_poolfc<<<NG / 4, 256, 0, stream>>>(bufB, batch, slotsB, bn2g, bn2b,
                                         fc1w, fc1b, fc2w, fc2b, fc3w, fc3b, outp);
}

// Round 15
// 260.478 us; speedup vs baseline: 2.8894x; 1.0472x over previous
//
#include <hip/hip_runtime.h>
#include <hip/hip_fp16.h>

#define NN 40000
#define NE 640000
#define DF 128
#define NG 2000
#define NCH 157        // ceil(NN/256) node windows (256-node)
#define FILLB 625      // NE / (256*4) edge blocks, 4 edges/thread
#define G1_BLKS 313    // ceil(NN/128) -- GEMM1 128-row tiles
#define G2_BLKS 625    // NN/64 -- GEMM2 64-row tiles
#define NCHUNK 64      // edge chunks
#define ECH 10000      // NE / NCHUNK
#define NOCT 8         // node eighths
#define QN 5120        // nodes per eighth (window-aligned: 20 windows of 256)
#define NPAD (NOCT * QN)   // 40960 padded nodes
#define NWIN 160       // NPAD / 256 windows
#define HISTB (NCHUNK * NOCT)  // 512 hist blocks

typedef unsigned int u32;
typedef __attribute__((ext_vector_type(8))) short short8;
typedef __attribute__((ext_vector_type(4))) float floatx4;

// ---- bf16 helpers (packed u32: low 16 = even col, high = odd col) ----
__device__ inline float2 bf2_to_f2(u32 u) {
    return make_float2(__uint_as_float(u << 16), __uint_as_float(u & 0xffff0000u));
}
__device__ inline u32 f_to_bf(float f) {
    u32 u = __float_as_uint(f);
    return (u + 0x7fffu + ((u >> 16) & 1u)) >> 16;   // RNE
}
__device__ inline u32 pack_bf2(float a, float b) {
    return f_to_bf(a) | (f_to_bf(b) << 16);
}
__device__ inline float bf_to_f(short s) {
    return __uint_as_float(((u32)(unsigned short)s) << 16);
}
// packed col entry: low 16 = src index (<65536), high 16 = fp16(dis[src])
__device__ inline float colw_to_f(int cw) {
    return __half2float(__ushort_as_half((unsigned short)((u32)cw >> 16)));
}

// ---------------- MFMA GEMM core (LDS passed in: uni 34816B union, sc/sh 128 floats) ----------------
template<bool BF16IN, bool FUSE_BN, bool WT_F32, bool TILE128>
__device__ __forceinline__ void gemm_core(const void* __restrict__ Xv, const void* __restrict__ wsrc,
                                          u32* __restrict__ outb, const float* __restrict__ slots,
                                          const float* __restrict__ gam, const float* __restrict__ bet,
                                          int bid, char* sbuf, float* sc, float* sh) {
    unsigned short* wlds = (unsigned short*)sbuf;
    unsigned short* clds = (unsigned short*)sbuf;
    int tid = threadIdx.x;
    int row0 = bid * (TILE128 ? 128 : 64);

    if (FUSE_BN) {
        if (tid < 128) {
            float s = 0.f, q = 0.f;
            for (int k = 0; k < 64; k++) {
                s += slots[k * 256 + tid];
                q += slots[k * 256 + 128 + tid];
            }
            const float inv_n = 1.0f / (float)NN;
            float mu = s * inv_n;
            float va = fmaf(-mu, mu, q * inv_n);
            float a = gam[tid] * rsqrtf(va + 1e-5f);
            sc[tid] = a;
            sh[tid] = fmaf(-mu, a, bet[tid]);
        }
    }
    if (WT_F32) {
        const float* W = (const float*)wsrc;     // W[k][c] row-major fp32
        for (int i = tid; i < 16384; i += 256) {
            int k = i >> 7, c = i & 127;
            wlds[c * 136 + k] = (unsigned short)f_to_bf(W[i]);
        }
    } else {
        const unsigned short* wt = (const unsigned short*)wsrc;   // pre-transposed bf16
        for (int i = tid; i < 2048; i += 256) {
            int c = i >> 4, s = i & 15;
            *(uint4*)&wlds[c * 136 + s * 8] = ((const uint4*)wt)[i];
        }
    }
    __syncthreads();

    int lane = tid & 63;
    int wave = tid >> 6;
    int qr = lane >> 4;
    int rl = lane & 15;

    if (TILE128) {
        int rA0 = row0 + wave * 32 + rl;
        int rA1 = rA0 + 16;
        int rA0c = rA0 < NN ? rA0 : NN - 1;
        int rA1c = rA1 < NN ? rA1 : NN - 1;
        floatx4 acc[2][8];
#pragma unroll
        for (int a = 0; a < 2; a++)
#pragma unroll
            for (int b = 0; b < 8; b++) acc[a][b] = (floatx4){0.f, 0.f, 0.f, 0.f};
#pragma unroll
        for (int kb = 0; kb < 4; kb++) {
            int k0 = kb * 32 + qr * 8;
            short8 a0, a1;
            if (!BF16IN) {
                const float* p0 = (const float*)Xv + (size_t)rA0c * DF + k0;
                const float* p1 = (const float*)Xv + (size_t)rA1c * DF + k0;
                float4 u0 = *(const float4*)p0, u1 = *(const float4*)(p0 + 4);
                float4 v0 = *(const float4*)p1, v1 = *(const float4*)(p1 + 4);
                float fa[8] = {u0.x, u0.y, u0.z, u0.w, u1.x, u1.y, u1.z, u1.w};
                float fb[8] = {v0.x, v0.y, v0.z, v0.w, v1.x, v1.y, v1.z, v1.w};
#pragma unroll
                for (int j = 0; j < 8; j++) { a0[j] = (short)f_to_bf(fa[j]); a1[j] = (short)f_to_bf(fb[j]); }
            } else {
                a0 = *(const short8*)((const u32*)Xv + (size_t)rA0c * 64 + (k0 >> 1));
                a1 = *(const short8*)((const u32*)Xv + (size_t)rA1c * 64 + (k0 >> 1));
                if (FUSE_BN) {
#pragma unroll
                    for (int j = 0; j < 8; j++) {
                        float f0 = fmaxf(fmaf(bf_to_f(a0[j]), sc[k0 + j], sh[k0 + j]), 0.f);
                        float f1 = fmaxf(fmaf(bf_to_f(a1[j]), sc[k0 + j], sh[k0 + j]), 0.f);
                        a0[j] = (short)f_to_bf(f0);
                        a1[j] = (short)f_to_bf(f1);
                    }
                }
            }
#pragma unroll
            for (int ct = 0; ct < 8; ct++) {
                short8 bfr = *(const short8*)&wlds[(ct * 16 + rl) * 136 + k0];
                acc[0][ct] = __builtin_amdgcn_mfma_f32_16x16x32_bf16(a0, bfr, acc[0][ct], 0, 0, 0);
                acc[1][ct] = __builtin_amdgcn_mfma_f32_16x16x32_bf16(a1, bfr, acc[1][ct], 0, 0, 0);
            }
        }
        __syncthreads();
#pragma unroll
        for (int rt = 0; rt < 2; rt++)
#pragma unroll
            for (int ct = 0; ct < 8; ct++)
#pragma unroll
                for (int r = 0; r < 4; r++) {
                    int lr = wave * 32 + rt * 16 + qr * 4 + r;
                    int c = ct * 16 + rl;
                    clds[lr * 136 + c] = (unsigned short)f_to_bf(acc[rt][ct][r]);
                }
        __syncthreads();
        for (int i = tid; i < 2048; i += 256) {
            int lr = i >> 4, s = i & 15;
            int grow = row0 + lr;
            if (grow < NN) {
                uint4 v = *(const uint4*)&clds[lr * 136 + s * 8];
                ((uint4*)(outb + (size_t)grow * 64))[s] = v;
            }
        }
    } else {
        int rA = row0 + wave * 16 + rl;   // < NN always (625*64 == NN)
        floatx4 acc[8];
#pragma unroll
        for (int b = 0; b < 8; b++) acc[b] = (floatx4){0.f, 0.f, 0.f, 0.f};
#pragma unroll
        for (int kb = 0; kb < 4; kb++) {
            int k0 = kb * 32 + qr * 8;
            short8 a0;
            if (!BF16IN) {
                const float* p0 = (const float*)Xv + (size_t)rA * DF + k0;
                float4 u0 = *(const float4*)p0, u1 = *(const float4*)(p0 + 4);
                float fa[8] = {u0.x, u0.y, u0.z, u0.w, u1.x, u1.y, u1.z, u1.w};
#pragma unroll
                for (int j = 0; j < 8; j++) a0[j] = (short)f_to_bf(fa[j]);
            } else {
                a0 = *(const short8*)((const u32*)Xv + (size_t)rA * 64 + (k0 >> 1));
                if (FUSE_BN) {
#pragma unroll
                    for (int j = 0; j < 8; j++) {
                        float f0 = fmaxf(fmaf(bf_to_f(a0[j]), sc[k0 + j], sh[k0 + j]), 0.f);
                        a0[j] = (short)f_to_bf(f0);
                    }
                }
            }
#pragma unroll
            for (int ct = 0; ct < 8; ct++) {
                short8 bfr = *(const short8*)&wlds[(ct * 16 + rl) * 136 + k0];
                acc[ct] = __builtin_amdgcn_mfma_f32_16x16x32_bf16(a0, bfr, acc[ct], 0, 0, 0);
            }
        }
        __syncthreads();
#pragma unroll
        for (int ct = 0; ct < 8; ct++)
#pragma unroll
            for (int r = 0; r < 4; r++) {
                int lr = wave * 16 + qr * 4 + r;
                int c = ct * 16 + rl;
                clds[lr * 136 + c] = (unsigned short)f_to_bf(acc[ct][r]);
            }
        __syncthreads();
        for (int i = tid; i < 1024; i += 256) {
            int lr = i >> 4, s = i & 15;
            uint4 v = *(const uint4*)&clds[lr * 136 + s * 8];
            ((uint4*)(outb + (size_t)(row0 + lr) * 64))[s] = v;
        }
    }
}

// ---------------- count: LDS-histogram (NO global atomics) + slots zero + wt2 + GEMM1 ----------------
// Block (c,oct) streams chunk c's dst (40KB, L2-hot), LDS-hist its 5120-node eighth,
// writes rank[e] (local rank), degT[c][n] slice, and exclusive window sums wsum[c][w].
__global__ __launch_bounds__(256, 4) void k_countgemm(const int* __restrict__ dst,
                                                      int* __restrict__ degT, int* __restrict__ rank,
                                                      int* __restrict__ wsum, float* __restrict__ slots0,
                                                      const float* __restrict__ W1, const float* __restrict__ W2,
                                                      unsigned short* __restrict__ wt2,
                                                      const float* __restrict__ X, u32* __restrict__ outb) {
    __shared__ __align__(16) char sbuf[34816];   // hist (20480B) / gemm wlds-clds union
    __shared__ float sc[128], sh[128];
    int bid = blockIdx.x;
    int tid = threadIdx.x;
    if (bid < HISTB) {
        int c = bid >> 3, oct = bid & 7;
        int nlo = oct * QN;
        int* hist = (int*)sbuf;
        for (int i = tid; i < QN; i += 256) hist[i] = 0;
        __syncthreads();
        int ebase = c * ECH;
        for (int i = tid; i < ECH; i += 256) {
            int d = dst[ebase + i];
            int t = d - nlo;
            if ((u32)t < (u32)QN) rank[ebase + i] = atomicAdd(&hist[t], 1);
        }
        __syncthreads();
        // degT slice (coalesced, non-atomic)
        for (int i = tid; i < QN; i += 256) degT[(size_t)c * NPAD + nlo + i] = hist[i];
        // window sums: 20 windows x 256 entries, wave wv handles windows wv,wv+4,...
        int wv = tid >> 6, lane = tid & 63;
        for (int lw = wv; lw < 20; lw += 4) {
            int v = hist[lw * 256 + lane] + hist[lw * 256 + 64 + lane]
                  + hist[lw * 256 + 128 + lane] + hist[lw * 256 + 192 + lane];
            for (int off = 32; off > 0; off >>= 1) v += __shfl_down(v, off);
            if (lane == 0) wsum[c * NWIN + oct * 20 + lw] = v;
        }
        return;
    }
    if (bid < HISTB + 2) {       // zero slotsA|slotsB (consumed 3+ dispatches later)
        float* s = slots0 + (size_t)(bid - HISTB) * 64 * 256;
        for (int i = tid; i < 64 * 256; i += 256) s[i] = 0.f;
        return;
    }
    if (bid == HISTB + 2) {      // wt2 transpose (consumed by k_gemm2, later dispatch)
        for (int i = tid; i < 128 * 128; i += 256) {
            int k = i >> 7, cc = i & 127;
            wt2[cc * 128 + k] = (unsigned short)f_to_bf(W2[i]);
        }
        return;
    }
    gemm_core<false, false, true, true>(X, W1, outb, nullptr, nullptr, nullptr,
                                        bid - HISTB - 3, sbuf, sc, sh);
}

// ---------------- scan: 157 window blocks; base from wsum; emits row_ptr, dis, baseT ----------------
__global__ __launch_bounds__(256) void k_scan(const int* __restrict__ degT, const int* __restrict__ wsum,
                                              int* __restrict__ baseT,
                                              int* __restrict__ row_ptr, float* __restrict__ dis) {
    __shared__ int red[256];
    __shared__ int ls[256];
    int tid = threadIdx.x;
    int wnd = blockIdx.x;
    // cross-window base: sum wsum[c][w'] for all c, w' < wnd
    int part = 0;
    for (int idx = tid; idx < NCHUNK * NWIN; idx += 256) {
        int wp = idx % NWIN;
        if (wp < wnd) part += wsum[idx];
    }
    red[tid] = part;
    // per-node chunk prefix
    int n = wnd * 256 + tid;    // < 40192 < NPAD, safe
    int run = 0;
#pragma unroll 4
    for (int c = 0; c < NCHUNK; c++) {
        int v = degT[(size_t)c * NPAD + n];
        baseT[(size_t)c * NPAD + n] = run;
        run += v;
    }
    int d = run;
    ls[tid] = d;
    __syncthreads();
#pragma unroll
    for (int off = 128; off > 0; off >>= 1) {
        if (tid < off) red[tid] += red[tid + off];
        __syncthreads();
    }
    int base = red[0];
#pragma unroll
    for (int off = 1; off < 256; off <<= 1) {
        int t = (tid >= off) ? ls[tid - off] : 0;
        __syncthreads();
        ls[tid] += t;
        __syncthreads();
    }
    if (n < NN) {
        int r = base + ls[tid] - d;   // global exclusive prefix
        row_ptr[n] = r;
        dis[n] = rsqrtf((float)(d + 1));
    }
    if (wnd == NCH - 1 && tid == 0) row_ptr[NN] = NE;
}

// ---------------- CSR fill: atomic-free; slot = row_ptr[d] + baseT[chunk][d] + rank[e] ----------------
__global__ __launch_bounds__(256) void k_fill(const int* __restrict__ src, const int* __restrict__ dst,
                                              const int* __restrict__ rank, const int* __restrict__ row_ptr,
                                              const int* __restrict__ baseT,
                                              const float* __restrict__ dis, u32* __restrict__ col) {
    int e0 = blockIdx.x * 1024 + threadIdx.x;
#pragma unroll
    for (int q = 0; q < 4; q++) {
        int e = e0 + q * 256;
        int d = dst[e];
        int s = src[e];
        int r = rank[e];
        int c = e / ECH;
        u32 h = (u32)__half_as_ushort(__float2half(dis[s]));
        col[row_ptr[d] + baseT[(size_t)c * NPAD + d] + r] = (u32)s | (h << 16);
    }
}

__global__ __launch_bounds__(256, 4) void k_gemm2(const u32* __restrict__ Hb, const unsigned short* __restrict__ wt2,
                                                  u32* __restrict__ outb, const float* __restrict__ slots,
                                                  const float* __restrict__ gam, const float* __restrict__ bet) {
    __shared__ __align__(16) char sbuf[34816];
    __shared__ float sc[128], sh[128];
    gemm_core<true, true, false, false>(Hb, wt2, outb, slots, gam, bet, blockIdx.x, sbuf, sc, sh);
}

// ---------------- GCN aggregation: one wave/node, 4 nodes/block; BN-stats fused ----------------
__global__ __launch_bounds__(256) void k_gather(const u32* __restrict__ Hb, const int* __restrict__ row_ptr,
                                                const u32* __restrict__ col, const float* __restrict__ dis,
                                                const float* __restrict__ bias, u32* __restrict__ outb,
                                                float* __restrict__ slots) {
    __shared__ float sred[4][128];
    __shared__ float qred[4][128];
    int t = threadIdx.x & 63;                       // lane: cols 2t, 2t+1
    int wv = threadIdx.x >> 6;
    int node = blockIdx.x * 4 + wv;
    float di = dis[node];
    float2 acc;
    {
        float2 a = bf2_to_f2(Hb[(size_t)node * 64 + t]);
        float s = di * di;
        acc = make_float2(a.x * s, a.y * s);
    }
    int lo = row_ptr[node], hi = row_ptr[node + 1];
    for (int base = lo; base < hi; base += 64) {
        int m = hi - base; if (m > 64) m = 64;
        int cw = 0;
        if (t < m) cw = (int)col[base + t];
        int j = 0;
        for (; j + 8 <= m; j += 8) {
            int c0 = __shfl(cw, j),     c1 = __shfl(cw, j + 1);
            int c2 = __shfl(cw, j + 2), c3 = __shfl(cw, j + 3);
            int c4 = __shfl(cw, j + 4), c5 = __shfl(cw, j + 5);
            int c6 = __shfl(cw, j + 6), c7 = __shfl(cw, j + 7);
            u32 u0 = Hb[(size_t)(c0 & 0xffff) * 64 + t], u1 = Hb[(size_t)(c1 & 0xffff) * 64 + t];
            u32 u2 = Hb[(size_t)(c2 & 0xffff) * 64 + t], u3 = Hb[(size_t)(c3 & 0xffff) * 64 + t];
            u32 u4 = Hb[(size_t)(c4 & 0xffff) * 64 + t], u5 = Hb[(size_t)(c5 & 0xffff) * 64 + t];
            u32 u6 = Hb[(size_t)(c6 & 0xffff) * 64 + t], u7 = Hb[(size_t)(c7 & 0xffff) * 64 + t];
            float w0 = di * colw_to_f(c0), w1 = di * colw_to_f(c1);
            float w2 = di * colw_to_f(c2), w3 = di * colw_to_f(c3);
            float w4 = di * colw_to_f(c4), w5 = di * colw_to_f(c5);
            float w6 = di * colw_to_f(c6), w7 = di * colw_to_f(c7);
            float2 h0 = bf2_to_f2(u0), h1 = bf2_to_f2(u1), h2 = bf2_to_f2(u2), h3 = bf2_to_f2(u3);
            float2 h4 = bf2_to_f2(u4), h5 = bf2_to_f2(u5), h6 = bf2_to_f2(u6), h7 = bf2_to_f2(u7);
            acc.x = fmaf(h3.x, w3, fmaf(h2.x, w2, fmaf(h1.x, w1, fmaf(h0.x, w0, acc.x))));
            acc.y = fmaf(h3.y, w3, fmaf(h2.y, w2, fmaf(h1.y, w1, fmaf(h0.y, w0, acc.y))));
            acc.x = fmaf(h7.x, w7, fmaf(h6.x, w6, fmaf(h5.x, w5, fmaf(h4.x, w4, acc.x))));
            acc.y = fmaf(h7.y, w7, fmaf(h6.y, w6, fmaf(h5.y, w5, fmaf(h4.y, w4, acc.y))));
        }
        for (; j < m; j++) {
            int c0 = __shfl(cw, j);
            float w0 = di * colw_to_f(c0);
            float2 h0 = bf2_to_f2(Hb[(size_t)(c0 & 0xffff) * 64 + t]);
            acc.x = fmaf(h0.x, w0, acc.x);
            acc.y = fmaf(h0.y, w0, acc.y);
        }
    }
    float2 b = ((const float2*)bias)[t];
    acc.x += b.x; acc.y += b.y;
    outb[(size_t)node * 64 + t] = pack_bf2(acc.x, acc.y);
    // BN stats (pre-BN activations, incl. bias): block reduce -> 64-slot atomics
    sred[wv][2 * t] = acc.x;     sred[wv][2 * t + 1] = acc.y;
    qred[wv][2 * t] = acc.x * acc.x; qred[wv][2 * t + 1] = acc.y * acc.y;
    __syncthreads();
    int tid = threadIdx.x;
    if (tid < 128) {
        float s = sred[0][tid] + sred[1][tid] + sred[2][tid] + sred[3][tid];
        float q = qred[0][tid] + qred[1][tid] + qred[2][tid] + qred[3][tid];
        int slot = blockIdx.x & 63;
        atomicAdd(&slots[slot * 256 + tid], s);
        atomicAdd(&slots[slot * 256 + 128 + tid], q);
    }
}

// ---------------- pool (BN2+ReLU) + fc1 + fc2 + fc3, 4 graphs per block ----------------
__global__ __launch_bounds__(256) void k_poolfc(const u32* __restrict__ Hb, const int* __restrict__ batch,
                                                const float* __restrict__ slots,
                                                const float* __restrict__ gam, const float* __restrict__ bet,
                                                const float* __restrict__ fc1w, const float* __restrict__ fc1b,
                                                const float* __restrict__ fc2w, const float* __restrict__ fc2b,
                                                const float* __restrict__ fc3w, const float* __restrict__ fc3b,
                                                float* __restrict__ out) {
    __shared__ float sc[128], sh[128];
    __shared__ float pooled[4][128];
    __shared__ float g1[4][256];
    __shared__ float g2[4][256];
    __shared__ int bnds[5];
    int tid = threadIdx.x;
    int gbase = blockIdx.x * 4;
    if (tid < 128) {
        float s = 0.f, q = 0.f;
        for (int k = 0; k < 64; k++) {
            s += slots[k * 256 + tid];
            q += slots[k * 256 + 128 + tid];
        }
        const float inv_n = 1.0f / (float)NN;
        float mu = s * inv_n;
        float va = fmaf(-mu, mu, q * inv_n);
        float a = gam[tid] * rsqrtf(va + 1e-5f);
        sc[tid] = a;
        sh[tid] = fmaf(-mu, a, bet[tid]);
    } else if (tid < 133) {
        int target = gbase + (tid - 128);
        int a = 0, b = NN;
        while (a < b) { int m = (a + b) >> 1; if (batch[m] < target) a = m + 1; else b = m; }
        bnds[tid - 128] = a;
    }
    __syncthreads();
    {
        int g = tid >> 6, p = tid & 63;
        int lo = bnds[g], hi = bnds[g + 1];
        float a0 = 0.f, a1 = 0.f;
        float sc0 = sc[2 * p], sh0 = sh[2 * p], sc1 = sc[2 * p + 1], sh1 = sh[2 * p + 1];
        for (int i = lo; i < hi; i++) {
            float2 v = bf2_to_f2(Hb[(size_t)i * 64 + p]);
            a0 += fmaxf(fmaf(v.x, sc0, sh0), 0.f);
            a1 += fmaxf(fmaf(v.y, sc1, sh1), 0.f);
        }
        pooled[g][2 * p] = a0;
        pooled[g][2 * p + 1] = a1;
    }
    __syncthreads();
    {
        float x0 = 0.f, x1 = 0.f, x2 = 0.f, x3 = 0.f;
        for (int k = 0; k < 128; k++) {
            float wv = fc1w[k * 256 + tid];
            x0 = fmaf(pooled[0][k], wv, x0);
            x1 = fmaf(pooled[1][k], wv, x1);
            x2 = fmaf(pooled[2][k], wv, x2);
            x3 = fmaf(pooled[3][k], wv, x3);
        }
        float bb = fc1b[tid];
        g1[0][tid] = fmaxf(x0 + bb, 0.f);
        g1[1][tid] = fmaxf(x1 + bb, 0.f);
        g1[2][tid] = fmaxf(x2 + bb, 0.f);
        g1[3][tid] = fmaxf(x3 + bb, 0.f);
    }
    __syncthreads();
    {
        float x0 = 0.f, x1 = 0.f, x2 = 0.f, x3 = 0.f;
        for (int k = 0; k < 256; k++) {
            float wv = fc2w[k * 256 + tid];
            x0 = fmaf(g1[0][k], wv, x0);
            x1 = fmaf(g1[1][k], wv, x1);
            x2 = fmaf(g1[2][k], wv, x2);
            x3 = fmaf(g1[3][k], wv, x3);
        }
        float bb = fc2b[tid];
        g2[0][tid] = fmaxf(x0 + bb, 0.f);
        g2[1][tid] = fmaxf(x1 + bb, 0.f);
        g2[2][tid] = fmaxf(x2 + bb, 0.f);
        g2[3][tid] = fmaxf(x3 + bb, 0.f);
    }
    __syncthreads();
    {
        int lane = tid & 63, wv = tid >> 6;
        float s = fmaf(g2[wv][lane], fc3w[lane],
                  fmaf(g2[wv][64 + lane], fc3w[64 + lane],
                  fmaf(g2[wv][128 + lane], fc3w[128 + lane],
                       g2[wv][192 + lane] * fc3w[192 + lane])));
        for (int off = 32; off > 0; off >>= 1) s += __shfl_down(s, off);
        if (lane == 0) out[gbase + wv] = s + fc3b[0];
    }
}

extern "C" void kernel_launch(void* const* d_in, const int* in_sizes, int n_in,
                              void* d_out, int out_size, void* d_ws, size_t ws_size,
                              hipStream_t stream) {
    const float* x    = (const float*)d_in[0];
    const int*   ei   = (const int*)d_in[1];
    const int*   batch= (const int*)d_in[2];
    const float* W1   = (const float*)d_in[4];
    const float* b1   = (const float*)d_in[5];
    const float* W2   = (const float*)d_in[6];
    const float* b2   = (const float*)d_in[7];
    const float* bn1g = (const float*)d_in[8];
    const float* bn1b = (const float*)d_in[9];
    const float* bn2g = (const float*)d_in[10];
    const float* bn2b = (const float*)d_in[11];
    const float* fc1w = (const float*)d_in[12];
    const float* fc1b = (const float*)d_in[13];
    const float* fc2w = (const float*)d_in[14];
    const float* fc2b = (const float*)d_in[15];
    const float* fc3w = (const float*)d_in[16];
    const float* fc3b = (const float*)d_in[17];
    const int* src = ei;
    const int* dst = ei + NE;
    float* outp = (float*)d_out;

    char* w = (char*)d_ws;
    size_t o = 0;
    auto alloc = [&](size_t bytes) -> char* {
        char* p = w + o;
        o = (o + bytes + 255) & ~(size_t)255;
        return p;
    };
    int*   degT    = (int*)alloc((size_t)NCHUNK * NPAD * 4);   // written fully, no zeroing
    int*   baseT   = (int*)alloc((size_t)NCHUNK * NPAD * 4);
    int*   wsum    = (int*)alloc((size_t)NCHUNK * NWIN * 4);
    float* slots0  = (float*)alloc((size_t)2 * 64 * 256 * 4);  // zeroed in count dispatch
    int*   row_ptr = (int*)alloc((size_t)(NN + 1) * 4);
    int*   rank    = (int*)alloc((size_t)NE * 4);
    u32*   col     = (u32*)alloc((size_t)NE * 4);
    float* dis     = (float*)alloc((size_t)NN * 4);
    unsigned short* wt2 = (unsigned short*)alloc(128 * 128 * 2);
    u32*   bufA    = (u32*)alloc((size_t)NN * 64 * 4);
    u32*   bufB    = (u32*)alloc((size_t)NN * 64 * 4);
    float* slotsA  = slots0;
    float* slotsB  = slots0 + 64 * 256;

    k_countgemm<<<HISTB + 3 + G1_BLKS, 256, 0, stream>>>(dst, degT, rank, wsum, slots0,
                                                         W1, W2, wt2, x, bufA);
    k_scan<<<NCH, 256, 0, stream>>>(degT, wsum, baseT, row_ptr, dis);
    k_fill<<<FILLB, 256, 0, stream>>>(src, dst, rank, row_ptr, baseT, dis, col);
    k_gather<<<NN / 4, 256, 0, stream>>>(bufA, row_ptr, col, dis, b1, bufB, slotsA);
    k_gemm2<<<G2_BLKS, 256, 0, stream>>>(bufB, wt2, bufA, slotsA, bn1g, bn1b);
    k_gather<<<NN / 4, 256, 0, stream>>>(bufA, row_ptr, col, dis, b2, bufB, slotsB);
    k_poolfc<<<NG / 4, 256, 0, stream>>>(bufB, batch, slotsB, bn2g, bn2b,
                                         fc1w, fc1b, fc2w, fc2b, fc3w, fc3b, outp);
}